// Round 3
// baseline (154.159 us; speedup 1.0000x reference)
//
#include <hip/hip_runtime.h>
#include <stdint.h>

#define NH     16
#define LSEQ   2048
#define DH     64
#define HDIM   1024
#define BATCH  2

typedef __attribute__((ext_vector_type(8))) short bf16x8;
typedef __attribute__((ext_vector_type(4))) short bf16x4;
typedef __attribute__((ext_vector_type(8))) unsigned short u16x8;
typedef __attribute__((ext_vector_type(4))) float f32x4;

// fp32 -> bf16 (RNE)
static __device__ inline unsigned short f2bs(float f) {
    union { float f; uint32_t u; } v; v.f = f;
    uint32_t u = v.u;
    return (unsigned short)((u + 0x7FFFu + ((u >> 16) & 1u)) >> 16);
}

#define GLOAD_LDS(gp, lp) \
    __builtin_amdgcn_global_load_lds((const __attribute__((address_space(1))) void*)(gp), \
                                     (__attribute__((address_space(3))) void*)(lp), 16, 0, 0)

// sqrt(0.125 * log2(e)) — folded into xb so (sQ)·(sK) carries the softmax scale
#define QK_SCALE 0.42466083f

// ---------------------------------------------------------------------------
// Kernel 1: prep. grid (32 lt, 32 bh) = 1024 blocks, 256 thr.
//  a) threads 0..127: W fp32 -> bf16 swizzled 128x64 tiles (128 chunks/block)
//  b) all threads: x -> xb (frag-major Q/K, scaled) and xt (frag-major V^T,
//     ks-group XOR-swizzled so attn's ds_read_b64 V loads are bank-conflict-free)
// ---------------------------------------------------------------------------
__global__ __launch_bounds__(256) void prep_kernel(const float* __restrict__ x,
                                                   const float* __restrict__ W,
                                                   unsigned short* __restrict__ xb,
                                                   unsigned short* __restrict__ xt,
                                                   unsigned short* __restrict__ wbt) {
    const int lt = blockIdx.x, bh = blockIdx.y;
    const int bid = bh * 32 + lt;
    const int t = threadIdx.x;

    if (t < 128) {
        const int gid = bid * 128 + t;
        const int n  = gid >> 7;
        const int kc = gid & 127;
        const float* src = W + (size_t)n * 1024 + kc * 8;
        float4 f0 = *(const float4*)(src);
        float4 f1 = *(const float4*)(src + 4);
        u16x8 v;
        v[0]=f2bs(f0.x); v[1]=f2bs(f0.y); v[2]=f2bs(f0.z); v[3]=f2bs(f0.w);
        v[4]=f2bs(f1.x); v[5]=f2bs(f1.y); v[6]=f2bs(f1.z); v[7]=f2bs(f1.w);
        const int nt = n >> 7, rn = n & 127;
        const int kt = kc >> 3, c = kc & 7;
        *(u16x8*)(wbt + (((size_t)nt * 16 + kt) * 128 + rn) * 64 + ((c ^ (rn & 7)) * 8)) = v;
    }

    const int b = bh >> 4, h = bh & 15;
    const int r = t >> 2, cp = t & 3;

    __shared__ __align__(16) unsigned short Sm[64][72];

    const float* src = x + ((size_t)(b * LSEQ + lt * 64 + r)) * HDIM + h * DH + cp * 16;
    float4 f0 = *(const float4*)(src);
    float4 f1 = *(const float4*)(src + 4);
    float4 f2 = *(const float4*)(src + 8);
    float4 f3 = *(const float4*)(src + 12);
    u16x8 lo, hi;
    lo[0]=f2bs(f0.x); lo[1]=f2bs(f0.y); lo[2]=f2bs(f0.z); lo[3]=f2bs(f0.w);
    lo[4]=f2bs(f1.x); lo[5]=f2bs(f1.y); lo[6]=f2bs(f1.z); lo[7]=f2bs(f1.w);
    hi[0]=f2bs(f2.x); hi[1]=f2bs(f2.y); hi[2]=f2bs(f2.z); hi[3]=f2bs(f2.w);
    hi[4]=f2bs(f3.x); hi[5]=f2bs(f3.y); hi[6]=f2bs(f3.z); hi[7]=f2bs(f3.w);
    u16x8 slo, shi;
    slo[0]=f2bs(f0.x*QK_SCALE); slo[1]=f2bs(f0.y*QK_SCALE); slo[2]=f2bs(f0.z*QK_SCALE); slo[3]=f2bs(f0.w*QK_SCALE);
    slo[4]=f2bs(f1.x*QK_SCALE); slo[5]=f2bs(f1.y*QK_SCALE); slo[6]=f2bs(f1.z*QK_SCALE); slo[7]=f2bs(f1.w*QK_SCALE);
    shi[0]=f2bs(f2.x*QK_SCALE); shi[1]=f2bs(f2.y*QK_SCALE); shi[2]=f2bs(f2.z*QK_SCALE); shi[3]=f2bs(f2.w*QK_SCALE);
    shi[4]=f2bs(f3.x*QK_SCALE); shi[5]=f2bs(f3.y*QK_SCALE); shi[6]=f2bs(f3.z*QK_SCALE); shi[7]=f2bs(f3.w*QK_SCALE);

    {
        unsigned short* kt = xb + ((size_t)bid) * 4096;
        const int s  = r >> 4, rla = r & 15;
        const int ks = cp >> 1, q0 = (cp & 1) * 2;
        *(u16x8*)(kt + ((s * 2 + ks) * 64 + q0 * 16 + rla) * 8)       = slo;
        *(u16x8*)(kt + ((s * 2 + ks) * 64 + (q0 + 1) * 16 + rla) * 8) = shi;
    }
    *(u16x8*)&Sm[r][cp * 16]     = lo;
    *(u16x8*)&Sm[r][cp * 16 + 8] = hi;
    __syncthreads();

    {
        const int dt = t >> 6, lane = t & 63;
        const int la = lane & 15, quad = lane >> 4;
        const int sw = (lane >> 2) & 3;   // row-dependent XOR for ks-group placement
        unsigned short* vt = xt + ((size_t)bid) * 4096;
        unsigned short* row = vt + (dt * 64 + lane) * 16;
        #pragma unroll
        for (int g = 0; g < 4; ++g) {
            ushort4 fr;
            fr.x = Sm[g * 16 + quad * 4 + 0][dt * 16 + la];
            fr.y = Sm[g * 16 + quad * 4 + 1][dt * 16 + la];
            fr.z = Sm[g * 16 + quad * 4 + 2][dt * 16 + la];
            fr.w = Sm[g * 16 + quad * 4 + 3][dt * 16 + la];
            *(ushort4*)(row + ((g ^ sw) * 4)) = fr;
        }
    }
}

// ---------------------------------------------------------------------------
// Kernel 2: flash attention, transpose-free.
// r13: 32 q-rows per wave (two 16-q subtiles) — K/V LDS frags read ONCE and
// fed to both q-chains, halving LDS read traffic (was the bottleneck pipe);
// V-frag reads XOR-deswizzled (conflict-free). grid (32 bh, 16 qt) = 512
// blocks, 256 thr (4 waves), 128 q/block, 2 blocks/CU.
// ---------------------------------------------------------------------------
__global__ __launch_bounds__(256) void attn_kernel(const unsigned short* __restrict__ xb,
                                                   const unsigned short* __restrict__ xt,
                                                   unsigned short* __restrict__ ctxt) {
    const int bh = blockIdx.x;
    const int qt = blockIdx.y;
    const int tid = threadIdx.x;
    const int w = tid >> 6, lane = tid & 63;
    const int la = lane & 15, quad = lane >> 4;
    const int vsw = (lane >> 2) & 3;

    __shared__ __align__(16) unsigned short KL[2][4096];
    __shared__ __align__(16) unsigned short VL[2][4096];

    const unsigned short* xbh = xb + (size_t)bh * 32 * 4096;
    const unsigned short* xth = xt + (size_t)bh * 32 * 4096;
    const int qbase = qt * 128 + w * 32;

    // two q-subtiles per wave: qf[qi][ks]
    bf16x8 qf[2][2];
    {
        const unsigned short* qs = xbh + (qbase >> 6) * 4096 + ((qbase >> 4) & 3) * 1024;
        qf[0][0] = *(const bf16x8*)(qs + lane * 8);
        qf[0][1] = *(const bf16x8*)(qs + 512 + lane * 8);
        qf[1][0] = *(const bf16x8*)(qs + 1024 + lane * 8);
        qf[1][1] = *(const bf16x8*)(qs + 1536 + lane * 8);
    }

    const f32x4 fzero = {0.f, 0.f, 0.f, 0.f};
    f32x4 acc0[4], acc1[4];
    #pragma unroll
    for (int j = 0; j < 4; ++j) { acc0[j] = fzero; acc1[j] = fzero; }
    float lp0 = 0.f, lp1 = 0.f;

    const int soff = tid * 16;                 // this thread's 16B staging slot
    #pragma unroll
    for (int j = 0; j < 2; ++j) {
        const int off = j * 4096 + soff;
        GLOAD_LDS((const char*)xbh + off, (char*)KL[0] + off);
        GLOAD_LDS((const char*)xth + off, (char*)VL[0] + off);
    }
    __syncthreads();

    // incremented staging source pointers (tile t+1)
    const char* kp = (const char*)xbh + 8192;
    const char* vp = (const char*)xth + 8192;

    for (int tt = 0; tt < 32; ++tt) {
        if (tt < 31) {
            char* kdst = (char*)KL[(tt + 1) & 1];
            GLOAD_LDS(kp + soff,        kdst + soff);
            GLOAD_LDS(kp + 4096 + soff, kdst + 4096 + soff);
        }

        // --- S^T = K Q^T for both q-subtiles, K-frags read once ---
        const unsigned short* kb = KL[tt & 1];
        bf16x4 pf0[4], pf1[4];
        {
            float ls0 = 0.f, ls1 = 0.f;
            #pragma unroll
            for (int kvt = 0; kvt < 4; ++kvt) {
                bf16x8 kf0 = *(const bf16x8*)(kb + (kvt * 2 + 0) * 512 + lane * 8);
                bf16x8 kf1 = *(const bf16x8*)(kb + (kvt * 2 + 1) * 512 + lane * 8);
                f32x4 s0 = fzero, s1 = fzero;
                s0 = __builtin_amdgcn_mfma_f32_16x16x32_bf16(kf0, qf[0][0], s0, 0, 0, 0);
                s0 = __builtin_amdgcn_mfma_f32_16x16x32_bf16(kf1, qf[0][1], s0, 0, 0, 0);
                s1 = __builtin_amdgcn_mfma_f32_16x16x32_bf16(kf0, qf[1][0], s1, 0, 0, 0);
                s1 = __builtin_amdgcn_mfma_f32_16x16x32_bf16(kf1, qf[1][1], s1, 0, 0, 0);

                // exp2 + truncation pack, q-subtile 0
                {
                    float p0 = __builtin_amdgcn_exp2f(s0[0]);
                    float p1 = __builtin_amdgcn_exp2f(s0[1]);
                    float p2 = __builtin_amdgcn_exp2f(s0[2]);
                    float p3 = __builtin_amdgcn_exp2f(s0[3]);
                    ls0 += (p0 + p1) + (p2 + p3);
                    union { uint2 u; bf16x4 v; } cv;
                    cv.u = make_uint2(
                        __builtin_amdgcn_perm(__float_as_uint(p1), __float_as_uint(p0), 0x07060302),
                        __builtin_amdgcn_perm(__float_as_uint(p3), __float_as_uint(p2), 0x07060302));
                    pf0[kvt] = cv.v;
                }
                // exp2 + truncation pack, q-subtile 1
                {
                    float p0 = __builtin_amdgcn_exp2f(s1[0]);
                    float p1 = __builtin_amdgcn_exp2f(s1[1]);
                    float p2 = __builtin_amdgcn_exp2f(s1[2]);
                    float p3 = __builtin_amdgcn_exp2f(s1[3]);
                    ls1 += (p0 + p1) + (p2 + p3);
                    union { uint2 u; bf16x4 v; } cv;
                    cv.u = make_uint2(
                        __builtin_amdgcn_perm(__float_as_uint(p1), __float_as_uint(p0), 0x07060302),
                        __builtin_amdgcn_perm(__float_as_uint(p3), __float_as_uint(p2), 0x07060302));
                    pf1[kvt] = cv.v;
                }
            }
            lp0 += ls0;
            lp1 += ls1;
        }

        __syncthreads();

        if (tt < 31) {
            char* vdst = (char*)VL[(tt + 1) & 1];
            GLOAD_LDS(vp + soff,        vdst + soff);
            GLOAD_LDS(vp + 4096 + soff, vdst + 4096 + soff);
            kp += 8192;
            vp += 8192;
        }

        // --- O^T += V^T P^T, V-frags read once (deswizzled), both q-chains ---
        const unsigned short* vb = VL[tt & 1];
        #pragma unroll
        for (int dt = 0; dt < 4; ++dt) {
            const unsigned short* vrow = vb + (dt * 64 + lane) * 16;
            bf16x4 vf0 = *(const bf16x4*)(vrow + ((0 ^ vsw) * 4));
            bf16x4 vf1 = *(const bf16x4*)(vrow + ((1 ^ vsw) * 4));
            bf16x4 vf2 = *(const bf16x4*)(vrow + ((2 ^ vsw) * 4));
            bf16x4 vf3 = *(const bf16x4*)(vrow + ((3 ^ vsw) * 4));
            f32x4 a0 = acc0[dt], a1 = acc1[dt];
            a0 = __builtin_amdgcn_mfma_f32_16x16x16bf16_1k(vf0, pf0[0], a0, 0, 0, 0);
            a0 = __builtin_amdgcn_mfma_f32_16x16x16bf16_1k(vf1, pf0[1], a0, 0, 0, 0);
            a0 = __builtin_amdgcn_mfma_f32_16x16x16bf16_1k(vf2, pf0[2], a0, 0, 0, 0);
            a0 = __builtin_amdgcn_mfma_f32_16x16x16bf16_1k(vf3, pf0[3], a0, 0, 0, 0);
            a1 = __builtin_amdgcn_mfma_f32_16x16x16bf16_1k(vf0, pf1[0], a1, 0, 0, 0);
            a1 = __builtin_amdgcn_mfma_f32_16x16x16bf16_1k(vf1, pf1[1], a1, 0, 0, 0);
            a1 = __builtin_amdgcn_mfma_f32_16x16x16bf16_1k(vf2, pf1[2], a1, 0, 0, 0);
            a1 = __builtin_amdgcn_mfma_f32_16x16x16bf16_1k(vf3, pf1[3], a1, 0, 0, 0);
            acc0[dt] = a0;
            acc1[dt] = a1;
        }
    }

    // --- epilogue: normalize in-register, write swizzled proj-A ctx tiles ---
    const int b = bh >> 4, h = bh & 15;
    const int mt = b * 16 + qt;
    unsigned short* tbase = ctxt + ((size_t)mt * 16 + h) * 128 * 64;
    {
        float l0 = lp0;
        l0 += __shfl_xor(l0, 16);
        l0 += __shfl_xor(l0, 32);
        float l1 = lp1;
        l1 += __shfl_xor(l1, 16);
        l1 += __shfl_xor(l1, 32);
        const float inv0 = 1.0f / l0;
        const float inv1 = 1.0f / l1;

        const int rr0 = w * 32 + la;
        unsigned short* rowp0 = tbase + rr0 * 64 + (quad & 1) * 4;
        #pragma unroll
        for (int dt = 0; dt < 4; ++dt) {
            f32x4 a = acc0[dt];
            const int c = dt * 2 + (quad >> 1);
            *(ushort4*)(rowp0 + ((c ^ (rr0 & 7)) * 8)) =
                make_ushort4(f2bs(a[0] * inv0), f2bs(a[1] * inv0),
                             f2bs(a[2] * inv0), f2bs(a[3] * inv0));
        }
        const int rr1 = w * 32 + 16 + la;
        unsigned short* rowp1 = tbase + rr1 * 64 + (quad & 1) * 4;
        #pragma unroll
        for (int dt = 0; dt < 4; ++dt) {
            f32x4 a = acc1[dt];
            const int c = dt * 2 + (quad >> 1);
            *(ushort4*)(rowp1 + ((c ^ (rr1 & 7)) * 8)) =
                make_ushort4(f2bs(a[0] * inv1), f2bs(a[1] * inv1),
                             f2bs(a[2] * inv1), f2bs(a[3] * inv1));
        }
    }
}

// ---------------------------------------------------------------------------
// Kernel 3: out = ctx @ W^T + b. 128x128 tile, BK=64, double-buffered LDS,
// one barrier/iter, flat global_load_lds of pre-swizzled tiles.
// grid (8 n, 32 m), block 256 = 4 waves (2x2 64x64 quadrants).
// ---------------------------------------------------------------------------
__global__ __launch_bounds__(256) void proj_kernel(const unsigned short* __restrict__ ctxt,
                                                   const unsigned short* __restrict__ wbt,
                                                   const float* __restrict__ bias,
                                                   float* __restrict__ out) {
    const int ntb = blockIdx.x;
    const int mtb = blockIdx.y;
    const int tid = threadIdx.x;
    const int w = tid >> 6, lane = tid & 63;
    const int la = lane & 15, quad = lane >> 4;
    const int wm = (w >> 1) * 64, wn = (w & 1) * 64;

    __shared__ __align__(16) unsigned short As[2][8192];
    __shared__ __align__(16) unsigned short Bs[2][8192];

    const unsigned short* abase = ctxt + (size_t)mtb * 16 * 8192;
    const unsigned short* bbase = wbt  + (size_t)ntb * 16 * 8192;

    const int sw0 = ((quad)     ^ (la & 7)) * 8;
    const int sw1 = ((quad + 4) ^ (la & 7)) * 8;

    const f32x4 fzero = {0.f, 0.f, 0.f, 0.f};
    f32x4 acc[4][4];
    #pragma unroll
    for (int i = 0; i < 4; ++i)
        #pragma unroll
        for (int j = 0; j < 4; ++j) acc[i][j] = fzero;

    #pragma unroll
    for (int j = 0; j < 4; ++j) {
        const int fc = j * 256 + tid;
        GLOAD_LDS((const char*)abase + fc * 16, (char*)As[0] + fc * 16);
        GLOAD_LDS((const char*)bbase + fc * 16, (char*)Bs[0] + fc * 16);
    }
    __syncthreads();

    for (int kt = 0; kt < 16; ++kt) {
        if (kt < 15) {
            const char* asrc = (const char*)(abase + (kt + 1) * 8192);
            const char* bsrc = (const char*)(bbase + (kt + 1) * 8192);
            char* adst = (char*)As[(kt + 1) & 1];
            char* bdst = (char*)Bs[(kt + 1) & 1];
            #pragma unroll
            for (int j = 0; j < 4; ++j) {
                const int fc = j * 256 + tid;
                GLOAD_LDS(asrc + fc * 16, adst + fc * 16);
                GLOAD_LDS(bsrc + fc * 16, bdst + fc * 16);
            }
        }

        const unsigned short* Ab = As[kt & 1];
        const unsigned short* Bb = Bs[kt & 1];
        #pragma unroll
        for (int ks2 = 0; ks2 < 2; ++ks2) {
            const int sw = ks2 ? sw1 : sw0;
            bf16x8 af[4], bfr[4];
            #pragma unroll
            for (int mt = 0; mt < 4; ++mt) af[mt]  = *(const bf16x8*)&Ab[(wm + mt * 16 + la) * 64 + sw];
            #pragma unroll
            for (int nt = 0; nt < 4; ++nt) bfr[nt] = *(const bf16x8*)&Bb[(wn + nt * 16 + la) * 64 + sw];
            #pragma unroll
            for (int mt = 0; mt < 4; ++mt)
                #pragma unroll
                for (int nt = 0; nt < 4; ++nt)
                    acc[mt][nt] = __builtin_amdgcn_mfma_f32_16x16x32_bf16(af[mt], bfr[nt], acc[mt][nt], 0, 0, 0);
        }
        __syncthreads();
    }

    const int m0 = mtb * 128, n0 = ntb * 128;
    #pragma unroll
    for (int nt = 0; nt < 4; ++nt) {
        const int n = n0 + wn + nt * 16 + la;
        const float bv = bias[n];
        #pragma unroll
        for (int mt = 0; mt < 4; ++mt)
            #pragma unroll
            for (int r = 0; r < 4; ++r) {
                const int m = m0 + wm + mt * 16 + quad * 4 + r;
                out[(size_t)m * HDIM + n] = acc[mt][nt][r] + bv;
            }
    }
}

// ---------------------------------------------------------------------------
extern "C" void kernel_launch(void* const* d_in, const int* in_sizes, int n_in,
                              void* d_out, int out_size, void* d_ws, size_t ws_size,
                              hipStream_t stream) {
    const float* x    = (const float*)d_in[0];
    const float* W    = (const float*)d_in[1];
    const float* bias = (const float*)d_in[2];
    float* out = (float*)d_out;

    // ws layout (bytes): ctxt 8M | xb 8M | xt 8M | wbt 2M
    unsigned short* ctxt = (unsigned short*)d_ws;
    unsigned short* xbp  = (unsigned short*)((char*)d_ws + ( 8u << 20));
    unsigned short* xtp  = (unsigned short*)((char*)d_ws + (16u << 20));
    unsigned short* wbt  = (unsigned short*)((char*)d_ws + (24u << 20));

    prep_kernel<<<dim3(32, 32), 256, 0, stream>>>(x, W, xbp, xtp, wbt);
    attn_kernel<<<dim3(32, 16), 256, 0, stream>>>(xbp, xtp, ctxt);
    proj_kernel<<<dim3(8, 32), 256, 0, stream>>>(ctxt, wbt, bias, out);
}

// Round 4
// 148.698 us; speedup vs baseline: 1.0367x; 1.0367x over previous
//
#include <hip/hip_runtime.h>
#include <stdint.h>

#define NH     16
#define LSEQ   2048
#define DH     64
#define HDIM   1024
#define BATCH  2

typedef __attribute__((ext_vector_type(8))) short bf16x8;
typedef __attribute__((ext_vector_type(4))) short bf16x4;
typedef __attribute__((ext_vector_type(8))) unsigned short u16x8;
typedef __attribute__((ext_vector_type(4))) float f32x4;

// fp32 -> bf16 (RNE)
static __device__ inline unsigned short f2bs(float f) {
    union { float f; uint32_t u; } v; v.f = f;
    uint32_t u = v.u;
    return (unsigned short)((u + 0x7FFFu + ((u >> 16) & 1u)) >> 16);
}

#define GLOAD_LDS(gp, lp) \
    __builtin_amdgcn_global_load_lds((const __attribute__((address_space(1))) void*)(gp), \
                                     (__attribute__((address_space(3))) void*)(lp), 16, 0, 0)

// sqrt(0.125 * log2(e)) — folded into xb so (sQ)·(sK) carries the softmax scale
#define QK_SCALE 0.42466083f

// ---------------------------------------------------------------------------
// Kernel 1: prep. grid (32 lt, 32 bh) = 1024 blocks, 256 thr.
//  a) threads 0..127: W fp32 -> bf16 swizzled 128x64 tiles (128 chunks/block)
//  b) all threads: x -> xb (frag-major Q/K, scaled) and xt (frag-major V^T,
//     ks-group XOR-swizzled so attn's ds_read_b64 V loads are bank-conflict-free)
// ---------------------------------------------------------------------------
__global__ __launch_bounds__(256) void prep_kernel(const float* __restrict__ x,
                                                   const float* __restrict__ W,
                                                   unsigned short* __restrict__ xb,
                                                   unsigned short* __restrict__ xt,
                                                   unsigned short* __restrict__ wbt) {
    const int lt = blockIdx.x, bh = blockIdx.y;
    const int bid = bh * 32 + lt;
    const int t = threadIdx.x;

    if (t < 128) {
        const int gid = bid * 128 + t;
        const int n  = gid >> 7;
        const int kc = gid & 127;
        const float* src = W + (size_t)n * 1024 + kc * 8;
        float4 f0 = *(const float4*)(src);
        float4 f1 = *(const float4*)(src + 4);
        u16x8 v;
        v[0]=f2bs(f0.x); v[1]=f2bs(f0.y); v[2]=f2bs(f0.z); v[3]=f2bs(f0.w);
        v[4]=f2bs(f1.x); v[5]=f2bs(f1.y); v[6]=f2bs(f1.z); v[7]=f2bs(f1.w);
        const int nt = n >> 7, rn = n & 127;
        const int kt = kc >> 3, c = kc & 7;
        *(u16x8*)(wbt + (((size_t)nt * 16 + kt) * 128 + rn) * 64 + ((c ^ (rn & 7)) * 8)) = v;
    }

    const int b = bh >> 4, h = bh & 15;
    const int r = t >> 2, cp = t & 3;

    __shared__ __align__(16) unsigned short Sm[64][72];

    const float* src = x + ((size_t)(b * LSEQ + lt * 64 + r)) * HDIM + h * DH + cp * 16;
    float4 f0 = *(const float4*)(src);
    float4 f1 = *(const float4*)(src + 4);
    float4 f2 = *(const float4*)(src + 8);
    float4 f3 = *(const float4*)(src + 12);
    u16x8 lo, hi;
    lo[0]=f2bs(f0.x); lo[1]=f2bs(f0.y); lo[2]=f2bs(f0.z); lo[3]=f2bs(f0.w);
    lo[4]=f2bs(f1.x); lo[5]=f2bs(f1.y); lo[6]=f2bs(f1.z); lo[7]=f2bs(f1.w);
    hi[0]=f2bs(f2.x); hi[1]=f2bs(f2.y); hi[2]=f2bs(f2.z); hi[3]=f2bs(f2.w);
    hi[4]=f2bs(f3.x); hi[5]=f2bs(f3.y); hi[6]=f2bs(f3.z); hi[7]=f2bs(f3.w);
    u16x8 slo, shi;
    slo[0]=f2bs(f0.x*QK_SCALE); slo[1]=f2bs(f0.y*QK_SCALE); slo[2]=f2bs(f0.z*QK_SCALE); slo[3]=f2bs(f0.w*QK_SCALE);
    slo[4]=f2bs(f1.x*QK_SCALE); slo[5]=f2bs(f1.y*QK_SCALE); slo[6]=f2bs(f1.z*QK_SCALE); slo[7]=f2bs(f1.w*QK_SCALE);
    shi[0]=f2bs(f2.x*QK_SCALE); shi[1]=f2bs(f2.y*QK_SCALE); shi[2]=f2bs(f2.z*QK_SCALE); shi[3]=f2bs(f2.w*QK_SCALE);
    shi[4]=f2bs(f3.x*QK_SCALE); shi[5]=f2bs(f3.y*QK_SCALE); shi[6]=f2bs(f3.z*QK_SCALE); shi[7]=f2bs(f3.w*QK_SCALE);

    {
        unsigned short* kt = xb + ((size_t)bid) * 4096;
        const int s  = r >> 4, rla = r & 15;
        const int ks = cp >> 1, q0 = (cp & 1) * 2;
        *(u16x8*)(kt + ((s * 2 + ks) * 64 + q0 * 16 + rla) * 8)       = slo;
        *(u16x8*)(kt + ((s * 2 + ks) * 64 + (q0 + 1) * 16 + rla) * 8) = shi;
    }
    *(u16x8*)&Sm[r][cp * 16]     = lo;
    *(u16x8*)&Sm[r][cp * 16 + 8] = hi;
    __syncthreads();

    {
        const int dt = t >> 6, lane = t & 63;
        const int la = lane & 15, quad = lane >> 4;
        const int sw = (lane >> 2) & 3;   // row-dependent XOR for ks-group placement
        unsigned short* vt = xt + ((size_t)bid) * 4096;
        unsigned short* row = vt + (dt * 64 + lane) * 16;
        #pragma unroll
        for (int g = 0; g < 4; ++g) {
            ushort4 fr;
            fr.x = Sm[g * 16 + quad * 4 + 0][dt * 16 + la];
            fr.y = Sm[g * 16 + quad * 4 + 1][dt * 16 + la];
            fr.z = Sm[g * 16 + quad * 4 + 2][dt * 16 + la];
            fr.w = Sm[g * 16 + quad * 4 + 3][dt * 16 + la];
            *(ushort4*)(row + ((g ^ sw) * 4)) = fr;
        }
    }
}

// ---------------------------------------------------------------------------
// Kernel 2: flash attention, transpose-free, 64-q blocks (4 blocks/CU).
// r14: r12 geometry (16 q-rows/wave, grid 32x32 = 1024 blocks — the measured
// best for barrier-drain hiding via 4 independent blocks/CU) + the r13
// V-read XOR-deswizzle (measured: SQ_LDS_BANK_CONFLICT 4.19M -> 0).
// ---------------------------------------------------------------------------
__global__ __launch_bounds__(256) void attn_kernel(const unsigned short* __restrict__ xb,
                                                   const unsigned short* __restrict__ xt,
                                                   unsigned short* __restrict__ ctxt) {
    const int bh = blockIdx.x;
    const int qt = blockIdx.y;
    const int tid = threadIdx.x;
    const int w = tid >> 6, lane = tid & 63;
    const int la = lane & 15, quad = lane >> 4;
    const int vsw = (lane >> 2) & 3;

    __shared__ __align__(16) unsigned short KL[2][4096];
    __shared__ __align__(16) unsigned short VL[2][4096];

    const unsigned short* xbh = xb + (size_t)bh * 32 * 4096;
    const unsigned short* xth = xt + (size_t)bh * 32 * 4096;
    const int qbase = qt * 64 + w * 16;

    bf16x8 qf[2];
    {
        const unsigned short* qs = xbh + (qbase >> 6) * 4096 + (((qbase >> 4) & 3) * 2) * 512;
        qf[0] = *(const bf16x8*)(qs + lane * 8);
        qf[1] = *(const bf16x8*)(qs + 512 + lane * 8);
    }

    const f32x4 fzero = {0.f, 0.f, 0.f, 0.f};
    f32x4 acc[4];
    #pragma unroll
    for (int j = 0; j < 4; ++j) acc[j] = fzero;
    float lp = 0.f;

    const int soff = tid * 16;                 // this thread's 16B staging slot
    #pragma unroll
    for (int j = 0; j < 2; ++j) {
        const int off = j * 4096 + soff;
        GLOAD_LDS((const char*)xbh + off, (char*)KL[0] + off);
        GLOAD_LDS((const char*)xth + off, (char*)VL[0] + off);
    }
    __syncthreads();

    // incremented staging source pointers (tile t+1)
    const char* kp = (const char*)xbh + 8192;
    const char* vp = (const char*)xth + 8192;

    for (int tt = 0; tt < 32; ++tt) {
        if (tt < 31) {
            char* kdst = (char*)KL[(tt + 1) & 1];
            GLOAD_LDS(kp + soff,        kdst + soff);
            GLOAD_LDS(kp + 4096 + soff, kdst + 4096 + soff);
        }

        // --- S^T = K Q^T ---
        const unsigned short* kb = KL[tt & 1];
        f32x4 st[4];
        #pragma unroll
        for (int kvt = 0; kvt < 4; ++kvt) {
            bf16x8 kf0 = *(const bf16x8*)(kb + (kvt * 2 + 0) * 512 + lane * 8);
            bf16x8 kf1 = *(const bf16x8*)(kb + (kvt * 2 + 1) * 512 + lane * 8);
            f32x4 s = fzero;
            s = __builtin_amdgcn_mfma_f32_16x16x32_bf16(kf0, qf[0], s, 0, 0, 0);
            s = __builtin_amdgcn_mfma_f32_16x16x32_bf16(kf1, qf[1], s, 0, 0, 0);
            st[kvt] = s;
        }

        // --- exp2 + truncation pack to register-resident B-frags ---
        bf16x4 pf[4];
        {
            float ls = 0.f;
            #pragma unroll
            for (int kvt = 0; kvt < 4; ++kvt) {
                float p0 = __builtin_amdgcn_exp2f(st[kvt][0]);
                float p1 = __builtin_amdgcn_exp2f(st[kvt][1]);
                float p2 = __builtin_amdgcn_exp2f(st[kvt][2]);
                float p3 = __builtin_amdgcn_exp2f(st[kvt][3]);
                ls += (p0 + p1) + (p2 + p3);
                union { uint2 u; bf16x4 v; } cv;
                cv.u = make_uint2(
                    __builtin_amdgcn_perm(__float_as_uint(p1), __float_as_uint(p0), 0x07060302),
                    __builtin_amdgcn_perm(__float_as_uint(p3), __float_as_uint(p2), 0x07060302));
                pf[kvt] = cv.v;
            }
            lp += ls;
        }

        __syncthreads();

        if (tt < 31) {
            char* vdst = (char*)VL[(tt + 1) & 1];
            GLOAD_LDS(vp + soff,        vdst + soff);
            GLOAD_LDS(vp + 4096 + soff, vdst + 4096 + soff);
            kp += 8192;
            vp += 8192;
        }

        // --- O^T += V^T P^T (XOR-deswizzled bf16x4 LDS loads, conflict-free) ---
        const unsigned short* vb = VL[tt & 1];
        #pragma unroll
        for (int dt = 0; dt < 4; ++dt) {
            const unsigned short* vrow = vb + (dt * 64 + lane) * 16;
            bf16x4 vf0 = *(const bf16x4*)(vrow + ((0 ^ vsw) * 4));
            bf16x4 vf1 = *(const bf16x4*)(vrow + ((1 ^ vsw) * 4));
            bf16x4 vf2 = *(const bf16x4*)(vrow + ((2 ^ vsw) * 4));
            bf16x4 vf3 = *(const bf16x4*)(vrow + ((3 ^ vsw) * 4));
            f32x4 a = acc[dt];
            a = __builtin_amdgcn_mfma_f32_16x16x16bf16_1k(vf0, pf[0], a, 0, 0, 0);
            a = __builtin_amdgcn_mfma_f32_16x16x16bf16_1k(vf1, pf[1], a, 0, 0, 0);
            a = __builtin_amdgcn_mfma_f32_16x16x16bf16_1k(vf2, pf[2], a, 0, 0, 0);
            a = __builtin_amdgcn_mfma_f32_16x16x16bf16_1k(vf3, pf[3], a, 0, 0, 0);
            acc[dt] = a;
        }
    }

    // --- epilogue: normalize in-register, write swizzled proj-A ctx tiles ---
    const int b = bh >> 4, h = bh & 15;
    const int mt = b * 16 + (qt >> 1);
    unsigned short* tbase = ctxt + ((size_t)mt * 16 + h) * 128 * 64;
    {
        float l = lp;
        l += __shfl_xor(l, 16);
        l += __shfl_xor(l, 32);
        const float inv = 1.0f / l;
        const int rr = (qt & 1) * 64 + w * 16 + la;
        unsigned short* rowp = tbase + rr * 64 + (quad & 1) * 4;
        #pragma unroll
        for (int dt = 0; dt < 4; ++dt) {
            f32x4 a = acc[dt];
            const int c = dt * 2 + (quad >> 1);
            *(ushort4*)(rowp + ((c ^ (rr & 7)) * 8)) =
                make_ushort4(f2bs(a[0] * inv), f2bs(a[1] * inv),
                             f2bs(a[2] * inv), f2bs(a[3] * inv));
        }
    }
}

// ---------------------------------------------------------------------------
// Kernel 3: out = ctx @ W^T + b. 128x128 tile, BK=64, double-buffered LDS,
// one barrier/iter, flat global_load_lds of pre-swizzled tiles.
// grid (8 n, 32 m), block 256 = 4 waves (2x2 64x64 quadrants).
// ---------------------------------------------------------------------------
__global__ __launch_bounds__(256) void proj_kernel(const unsigned short* __restrict__ ctxt,
                                                   const unsigned short* __restrict__ wbt,
                                                   const float* __restrict__ bias,
                                                   float* __restrict__ out) {
    const int ntb = blockIdx.x;
    const int mtb = blockIdx.y;
    const int tid = threadIdx.x;
    const int w = tid >> 6, lane = tid & 63;
    const int la = lane & 15, quad = lane >> 4;
    const int wm = (w >> 1) * 64, wn = (w & 1) * 64;

    __shared__ __align__(16) unsigned short As[2][8192];
    __shared__ __align__(16) unsigned short Bs[2][8192];

    const unsigned short* abase = ctxt + (size_t)mtb * 16 * 8192;
    const unsigned short* bbase = wbt  + (size_t)ntb * 16 * 8192;

    const int sw0 = ((quad)     ^ (la & 7)) * 8;
    const int sw1 = ((quad + 4) ^ (la & 7)) * 8;

    const f32x4 fzero = {0.f, 0.f, 0.f, 0.f};
    f32x4 acc[4][4];
    #pragma unroll
    for (int i = 0; i < 4; ++i)
        #pragma unroll
        for (int j = 0; j < 4; ++j) acc[i][j] = fzero;

    #pragma unroll
    for (int j = 0; j < 4; ++j) {
        const int fc = j * 256 + tid;
        GLOAD_LDS((const char*)abase + fc * 16, (char*)As[0] + fc * 16);
        GLOAD_LDS((const char*)bbase + fc * 16, (char*)Bs[0] + fc * 16);
    }
    __syncthreads();

    for (int kt = 0; kt < 16; ++kt) {
        if (kt < 15) {
            const char* asrc = (const char*)(abase + (kt + 1) * 8192);
            const char* bsrc = (const char*)(bbase + (kt + 1) * 8192);
            char* adst = (char*)As[(kt + 1) & 1];
            char* bdst = (char*)Bs[(kt + 1) & 1];
            #pragma unroll
            for (int j = 0; j < 4; ++j) {
                const int fc = j * 256 + tid;
                GLOAD_LDS(asrc + fc * 16, adst + fc * 16);
                GLOAD_LDS(bsrc + fc * 16, bdst + fc * 16);
            }
        }

        const unsigned short* Ab = As[kt & 1];
        const unsigned short* Bb = Bs[kt & 1];
        #pragma unroll
        for (int ks2 = 0; ks2 < 2; ++ks2) {
            const int sw = ks2 ? sw1 : sw0;
            bf16x8 af[4], bfr[4];
            #pragma unroll
            for (int mt = 0; mt < 4; ++mt) af[mt]  = *(const bf16x8*)&Ab[(wm + mt * 16 + la) * 64 + sw];
            #pragma unroll
            for (int nt = 0; nt < 4; ++nt) bfr[nt] = *(const bf16x8*)&Bb[(wn + nt * 16 + la) * 64 + sw];
            #pragma unroll
            for (int mt = 0; mt < 4; ++mt)
                #pragma unroll
                for (int nt = 0; nt < 4; ++nt)
                    acc[mt][nt] = __builtin_amdgcn_mfma_f32_16x16x32_bf16(af[mt], bfr[nt], acc[mt][nt], 0, 0, 0);
        }
        __syncthreads();
    }

    const int m0 = mtb * 128, n0 = ntb * 128;
    #pragma unroll
    for (int nt = 0; nt < 4; ++nt) {
        const int n = n0 + wn + nt * 16 + la;
        const float bv = bias[n];
        #pragma unroll
        for (int mt = 0; mt < 4; ++mt)
            #pragma unroll
            for (int r = 0; r < 4; ++r) {
                const int m = m0 + wm + mt * 16 + quad * 4 + r;
                out[(size_t)m * HDIM + n] = acc[mt][nt][r] + bv;
            }
    }
}

// ---------------------------------------------------------------------------
extern "C" void kernel_launch(void* const* d_in, const int* in_sizes, int n_in,
                              void* d_out, int out_size, void* d_ws, size_t ws_size,
                              hipStream_t stream) {
    const float* x    = (const float*)d_in[0];
    const float* W    = (const float*)d_in[1];
    const float* bias = (const float*)d_in[2];
    float* out = (float*)d_out;

    // ws layout (bytes): ctxt 8M | xb 8M | xt 8M | wbt 2M
    unsigned short* ctxt = (unsigned short*)d_ws;
    unsigned short* xbp  = (unsigned short*)((char*)d_ws + ( 8u << 20));
    unsigned short* xtp  = (unsigned short*)((char*)d_ws + (16u << 20));
    unsigned short* wbt  = (unsigned short*)((char*)d_ws + (24u << 20));

    prep_kernel<<<dim3(32, 32), 256, 0, stream>>>(x, W, xbp, xtp, wbt);
    attn_kernel<<<dim3(32, 32), 256, 0, stream>>>(xbp, xtp, ctxt);
    proj_kernel<<<dim3(8, 32), 256, 0, stream>>>(ctxt, wbt, bias, out);
}

// Round 5
// 144.883 us; speedup vs baseline: 1.0640x; 1.0263x over previous
//
#include <hip/hip_runtime.h>
#include <stdint.h>

#define NH     16
#define LSEQ   2048
#define DH     64
#define HDIM   1024
#define BATCH  2

typedef __attribute__((ext_vector_type(8))) short bf16x8;
typedef __attribute__((ext_vector_type(4))) short bf16x4;
typedef __attribute__((ext_vector_type(8))) unsigned short u16x8;
typedef __attribute__((ext_vector_type(4))) float f32x4;

// fp32 -> bf16 (RNE)
static __device__ inline unsigned short f2bs(float f) {
    union { float f; uint32_t u; } v; v.f = f;
    uint32_t u = v.u;
    return (unsigned short)((u + 0x7FFFu + ((u >> 16) & 1u)) >> 16);
}

#define GLOAD_LDS(gp, lp) \
    __builtin_amdgcn_global_load_lds((const __attribute__((address_space(1))) void*)(gp), \
                                     (__attribute__((address_space(3))) void*)(lp), 16, 0, 0)

// sqrt(0.125 * log2(e)) — folded into xb so (sQ)·(sK) carries the softmax scale
#define QK_SCALE 0.42466083f

// ---------------------------------------------------------------------------
// Kernel 1: prep. grid (32 lt, 32 bh) = 1024 blocks, 256 thr.
//  a) threads 0..127: W fp32 -> bf16 swizzled 128x64 tiles (128 chunks/block)
//  b) all threads: x -> xb (frag-major Q/K, scaled) and xt (frag-major V^T,
//     ks-group XOR-swizzled so attn's ds_read_b64 V loads are bank-conflict-free)
// ---------------------------------------------------------------------------
__global__ __launch_bounds__(256) void prep_kernel(const float* __restrict__ x,
                                                   const float* __restrict__ W,
                                                   unsigned short* __restrict__ xb,
                                                   unsigned short* __restrict__ xt,
                                                   unsigned short* __restrict__ wbt) {
    const int lt = blockIdx.x, bh = blockIdx.y;
    const int bid = bh * 32 + lt;
    const int t = threadIdx.x;

    if (t < 128) {
        const int gid = bid * 128 + t;
        const int n  = gid >> 7;
        const int kc = gid & 127;
        const float* src = W + (size_t)n * 1024 + kc * 8;
        float4 f0 = *(const float4*)(src);
        float4 f1 = *(const float4*)(src + 4);
        u16x8 v;
        v[0]=f2bs(f0.x); v[1]=f2bs(f0.y); v[2]=f2bs(f0.z); v[3]=f2bs(f0.w);
        v[4]=f2bs(f1.x); v[5]=f2bs(f1.y); v[6]=f2bs(f1.z); v[7]=f2bs(f1.w);
        const int nt = n >> 7, rn = n & 127;
        const int kt = kc >> 3, c = kc & 7;
        *(u16x8*)(wbt + (((size_t)nt * 16 + kt) * 128 + rn) * 64 + ((c ^ (rn & 7)) * 8)) = v;
    }

    const int b = bh >> 4, h = bh & 15;
    const int r = t >> 2, cp = t & 3;

    __shared__ __align__(16) unsigned short Sm[64][72];

    const float* src = x + ((size_t)(b * LSEQ + lt * 64 + r)) * HDIM + h * DH + cp * 16;
    float4 f0 = *(const float4*)(src);
    float4 f1 = *(const float4*)(src + 4);
    float4 f2 = *(const float4*)(src + 8);
    float4 f3 = *(const float4*)(src + 12);
    u16x8 lo, hi;
    lo[0]=f2bs(f0.x); lo[1]=f2bs(f0.y); lo[2]=f2bs(f0.z); lo[3]=f2bs(f0.w);
    lo[4]=f2bs(f1.x); lo[5]=f2bs(f1.y); lo[6]=f2bs(f1.z); lo[7]=f2bs(f1.w);
    hi[0]=f2bs(f2.x); hi[1]=f2bs(f2.y); hi[2]=f2bs(f2.z); hi[3]=f2bs(f2.w);
    hi[4]=f2bs(f3.x); hi[5]=f2bs(f3.y); hi[6]=f2bs(f3.z); hi[7]=f2bs(f3.w);
    u16x8 slo, shi;
    slo[0]=f2bs(f0.x*QK_SCALE); slo[1]=f2bs(f0.y*QK_SCALE); slo[2]=f2bs(f0.z*QK_SCALE); slo[3]=f2bs(f0.w*QK_SCALE);
    slo[4]=f2bs(f1.x*QK_SCALE); slo[5]=f2bs(f1.y*QK_SCALE); slo[6]=f2bs(f1.z*QK_SCALE); slo[7]=f2bs(f1.w*QK_SCALE);
    shi[0]=f2bs(f2.x*QK_SCALE); shi[1]=f2bs(f2.y*QK_SCALE); shi[2]=f2bs(f2.z*QK_SCALE); shi[3]=f2bs(f2.w*QK_SCALE);
    shi[4]=f2bs(f3.x*QK_SCALE); shi[5]=f2bs(f3.y*QK_SCALE); shi[6]=f2bs(f3.z*QK_SCALE); shi[7]=f2bs(f3.w*QK_SCALE);

    {
        unsigned short* kt = xb + ((size_t)bid) * 4096;
        const int s  = r >> 4, rla = r & 15;
        const int ks = cp >> 1, q0 = (cp & 1) * 2;
        *(u16x8*)(kt + ((s * 2 + ks) * 64 + q0 * 16 + rla) * 8)       = slo;
        *(u16x8*)(kt + ((s * 2 + ks) * 64 + (q0 + 1) * 16 + rla) * 8) = shi;
    }
    *(u16x8*)&Sm[r][cp * 16]     = lo;
    *(u16x8*)&Sm[r][cp * 16 + 8] = hi;
    __syncthreads();

    {
        const int dt = t >> 6, lane = t & 63;
        const int la = lane & 15, quad = lane >> 4;
        const int sw = (lane >> 2) & 3;   // row-dependent XOR for ks-group placement
        unsigned short* vt = xt + ((size_t)bid) * 4096;
        unsigned short* row = vt + (dt * 64 + lane) * 16;
        #pragma unroll
        for (int g = 0; g < 4; ++g) {
            ushort4 fr;
            fr.x = Sm[g * 16 + quad * 4 + 0][dt * 16 + la];
            fr.y = Sm[g * 16 + quad * 4 + 1][dt * 16 + la];
            fr.z = Sm[g * 16 + quad * 4 + 2][dt * 16 + la];
            fr.w = Sm[g * 16 + quad * 4 + 3][dt * 16 + la];
            *(ushort4*)(row + ((g ^ sw) * 4)) = fr;
        }
    }
}

// ---------------------------------------------------------------------------
// Kernel 2: flash attention, transpose-free.
// r15: r13 geometry (32 q/wave, 512 blocks — half the LDS traffic of r12)
// + depth-2 prefetch pipeline: 4 LDS buffers, raw s_barrier, counted
// s_waitcnt vmcnt(4) — prefetch for tile t+2 stays IN FLIGHT across the
// barrier (never drain to 0 in the loop). Removes the per-iteration
// vmcnt(0) drain that made r12/r13 latency-bound.
// grid (32 bh, 16 qt) = 512 blocks, 256 thr, LDS 64KB -> 2 blocks/CU.
// ---------------------------------------------------------------------------
__global__ __launch_bounds__(256) void attn_kernel(const unsigned short* __restrict__ xb,
                                                   const unsigned short* __restrict__ xt,
                                                   unsigned short* __restrict__ ctxt) {
    const int bh = blockIdx.x;
    const int qt = blockIdx.y;
    const int tid = threadIdx.x;
    const int w = tid >> 6, lane = tid & 63;
    const int la = lane & 15, quad = lane >> 4;
    const int vsw = (lane >> 2) & 3;

    __shared__ __align__(16) unsigned short KL[4][4096];
    __shared__ __align__(16) unsigned short VL[4][4096];

    const unsigned short* xbh = xb + (size_t)bh * 32 * 4096;
    const unsigned short* xth = xt + (size_t)bh * 32 * 4096;
    const int qbase = qt * 128 + w * 32;

    // two q-subtiles per wave: qf[qi][ks]
    bf16x8 qf[2][2];
    {
        const unsigned short* qs = xbh + (qbase >> 6) * 4096 + ((qbase >> 4) & 3) * 1024;
        qf[0][0] = *(const bf16x8*)(qs + lane * 8);
        qf[0][1] = *(const bf16x8*)(qs + 512 + lane * 8);
        qf[1][0] = *(const bf16x8*)(qs + 1024 + lane * 8);
        qf[1][1] = *(const bf16x8*)(qs + 1536 + lane * 8);
    }

    const f32x4 fzero = {0.f, 0.f, 0.f, 0.f};
    f32x4 acc0[4], acc1[4];
    #pragma unroll
    for (int j = 0; j < 4; ++j) { acc0[j] = fzero; acc1[j] = fzero; }
    float lp0 = 0.f, lp1 = 0.f;

    const int soff = tid * 16;                 // this thread's 16B staging slot

    // prologue: stage tiles 0 and 1 (pf(0), pf(1); 8 loads/thread)
    #pragma unroll
    for (int j = 0; j < 2; ++j) {
        const char* kps = (const char*)xbh + j * 8192;
        const char* vps = (const char*)xth + j * 8192;
        GLOAD_LDS(kps + soff,        (char*)KL[j] + soff);
        GLOAD_LDS(kps + 4096 + soff, (char*)KL[j] + 4096 + soff);
        GLOAD_LDS(vps + soff,        (char*)VL[j] + soff);
        GLOAD_LDS(vps + 4096 + soff, (char*)VL[j] + 4096 + soff);
    }
    // wait pf(0) (allow pf(1)'s 4 newest in flight), then barrier
    asm volatile("s_waitcnt vmcnt(4)" ::: "memory");
    __builtin_amdgcn_s_barrier();

    for (int tt = 0; tt < 32; ++tt) {
        // issue pf(tt+2): lands >= 2 barriers after the last reader of buf (tt+2)&3
        if (tt < 30) {
            const char* kps = (const char*)xbh + (tt + 2) * 8192;
            const char* vps = (const char*)xth + (tt + 2) * 8192;
            char* kdst = (char*)KL[(tt + 2) & 3];
            char* vdst = (char*)VL[(tt + 2) & 3];
            GLOAD_LDS(kps + soff,        kdst + soff);
            GLOAD_LDS(kps + 4096 + soff, kdst + 4096 + soff);
            GLOAD_LDS(vps + soff,        vdst + soff);
            GLOAD_LDS(vps + 4096 + soff, vdst + 4096 + soff);
        }

        // --- S^T = K Q^T for both q-subtiles, K-frags read once ---
        const unsigned short* kb = KL[tt & 3];
        bf16x4 pf0[4], pf1[4];
        {
            float ls0 = 0.f, ls1 = 0.f;
            #pragma unroll
            for (int kvt = 0; kvt < 4; ++kvt) {
                bf16x8 kf0 = *(const bf16x8*)(kb + (kvt * 2 + 0) * 512 + lane * 8);
                bf16x8 kf1 = *(const bf16x8*)(kb + (kvt * 2 + 1) * 512 + lane * 8);
                f32x4 s0 = fzero, s1 = fzero;
                s0 = __builtin_amdgcn_mfma_f32_16x16x32_bf16(kf0, qf[0][0], s0, 0, 0, 0);
                s0 = __builtin_amdgcn_mfma_f32_16x16x32_bf16(kf1, qf[0][1], s0, 0, 0, 0);
                s1 = __builtin_amdgcn_mfma_f32_16x16x32_bf16(kf0, qf[1][0], s1, 0, 0, 0);
                s1 = __builtin_amdgcn_mfma_f32_16x16x32_bf16(kf1, qf[1][1], s1, 0, 0, 0);

                // exp2 + truncation pack, q-subtile 0
                {
                    float p0 = __builtin_amdgcn_exp2f(s0[0]);
                    float p1 = __builtin_amdgcn_exp2f(s0[1]);
                    float p2 = __builtin_amdgcn_exp2f(s0[2]);
                    float p3 = __builtin_amdgcn_exp2f(s0[3]);
                    ls0 += (p0 + p1) + (p2 + p3);
                    union { uint2 u; bf16x4 v; } cv;
                    cv.u = make_uint2(
                        __builtin_amdgcn_perm(__float_as_uint(p1), __float_as_uint(p0), 0x07060302),
                        __builtin_amdgcn_perm(__float_as_uint(p3), __float_as_uint(p2), 0x07060302));
                    pf0[kvt] = cv.v;
                }
                // exp2 + truncation pack, q-subtile 1
                {
                    float p0 = __builtin_amdgcn_exp2f(s1[0]);
                    float p1 = __builtin_amdgcn_exp2f(s1[1]);
                    float p2 = __builtin_amdgcn_exp2f(s1[2]);
                    float p3 = __builtin_amdgcn_exp2f(s1[3]);
                    ls1 += (p0 + p1) + (p2 + p3);
                    union { uint2 u; bf16x4 v; } cv;
                    cv.u = make_uint2(
                        __builtin_amdgcn_perm(__float_as_uint(p1), __float_as_uint(p0), 0x07060302),
                        __builtin_amdgcn_perm(__float_as_uint(p3), __float_as_uint(p2), 0x07060302));
                    pf1[kvt] = cv.v;
                }
            }
            lp0 += ls0;
            lp1 += ls1;
        }

        // counted wait: pf(tt+1) guaranteed landed; pf(tt+2) stays in flight.
        if (tt < 30) {
            asm volatile("s_waitcnt vmcnt(4)" ::: "memory");
        } else {
            asm volatile("s_waitcnt vmcnt(0)" ::: "memory");
        }
        __builtin_amdgcn_s_barrier();

        // --- O^T += V^T P^T, V-frags read once (deswizzled), both q-chains ---
        const unsigned short* vb = VL[tt & 3];
        #pragma unroll
        for (int dt = 0; dt < 4; ++dt) {
            const unsigned short* vrow = vb + (dt * 64 + lane) * 16;
            bf16x4 vf0 = *(const bf16x4*)(vrow + ((0 ^ vsw) * 4));
            bf16x4 vf1 = *(const bf16x4*)(vrow + ((1 ^ vsw) * 4));
            bf16x4 vf2 = *(const bf16x4*)(vrow + ((2 ^ vsw) * 4));
            bf16x4 vf3 = *(const bf16x4*)(vrow + ((3 ^ vsw) * 4));
            f32x4 a0 = acc0[dt], a1 = acc1[dt];
            a0 = __builtin_amdgcn_mfma_f32_16x16x16bf16_1k(vf0, pf0[0], a0, 0, 0, 0);
            a0 = __builtin_amdgcn_mfma_f32_16x16x16bf16_1k(vf1, pf0[1], a0, 0, 0, 0);
            a0 = __builtin_amdgcn_mfma_f32_16x16x16bf16_1k(vf2, pf0[2], a0, 0, 0, 0);
            a0 = __builtin_amdgcn_mfma_f32_16x16x16bf16_1k(vf3, pf0[3], a0, 0, 0, 0);
            a1 = __builtin_amdgcn_mfma_f32_16x16x16bf16_1k(vf0, pf1[0], a1, 0, 0, 0);
            a1 = __builtin_amdgcn_mfma_f32_16x16x16bf16_1k(vf1, pf1[1], a1, 0, 0, 0);
            a1 = __builtin_amdgcn_mfma_f32_16x16x16bf16_1k(vf2, pf1[2], a1, 0, 0, 0);
            a1 = __builtin_amdgcn_mfma_f32_16x16x16bf16_1k(vf3, pf1[3], a1, 0, 0, 0);
            acc0[dt] = a0;
            acc1[dt] = a1;
        }
    }

    // --- epilogue: normalize in-register, write swizzled proj-A ctx tiles ---
    const int b = bh >> 4, h = bh & 15;
    const int mt = b * 16 + qt;
    unsigned short* tbase = ctxt + ((size_t)mt * 16 + h) * 128 * 64;
    {
        float l0 = lp0;
        l0 += __shfl_xor(l0, 16);
        l0 += __shfl_xor(l0, 32);
        float l1 = lp1;
        l1 += __shfl_xor(l1, 16);
        l1 += __shfl_xor(l1, 32);
        const float inv0 = 1.0f / l0;
        const float inv1 = 1.0f / l1;

        const int rr0 = w * 32 + la;
        unsigned short* rowp0 = tbase + rr0 * 64 + (quad & 1) * 4;
        #pragma unroll
        for (int dt = 0; dt < 4; ++dt) {
            f32x4 a = acc0[dt];
            const int c = dt * 2 + (quad >> 1);
            *(ushort4*)(rowp0 + ((c ^ (rr0 & 7)) * 8)) =
                make_ushort4(f2bs(a[0] * inv0), f2bs(a[1] * inv0),
                             f2bs(a[2] * inv0), f2bs(a[3] * inv0));
        }
        const int rr1 = w * 32 + 16 + la;
        unsigned short* rowp1 = tbase + rr1 * 64 + (quad & 1) * 4;
        #pragma unroll
        for (int dt = 0; dt < 4; ++dt) {
            f32x4 a = acc1[dt];
            const int c = dt * 2 + (quad >> 1);
            *(ushort4*)(rowp1 + ((c ^ (rr1 & 7)) * 8)) =
                make_ushort4(f2bs(a[0] * inv1), f2bs(a[1] * inv1),
                             f2bs(a[2] * inv1), f2bs(a[3] * inv1));
        }
    }
}

// ---------------------------------------------------------------------------
// Kernel 3: out = ctx @ W^T + b. 128x128 tile, BK=64, double-buffered LDS,
// one barrier/iter, flat global_load_lds of pre-swizzled tiles.
// grid (8 n, 32 m), block 256 = 4 waves (2x2 64x64 quadrants).
// ---------------------------------------------------------------------------
__global__ __launch_bounds__(256) void proj_kernel(const unsigned short* __restrict__ ctxt,
                                                   const unsigned short* __restrict__ wbt,
                                                   const float* __restrict__ bias,
                                                   float* __restrict__ out) {
    const int ntb = blockIdx.x;
    const int mtb = blockIdx.y;
    const int tid = threadIdx.x;
    const int w = tid >> 6, lane = tid & 63;
    const int la = lane & 15, quad = lane >> 4;
    const int wm = (w >> 1) * 64, wn = (w & 1) * 64;

    __shared__ __align__(16) unsigned short As[2][8192];
    __shared__ __align__(16) unsigned short Bs[2][8192];

    const unsigned short* abase = ctxt + (size_t)mtb * 16 * 8192;
    const unsigned short* bbase = wbt  + (size_t)ntb * 16 * 8192;

    const int sw0 = ((quad)     ^ (la & 7)) * 8;
    const int sw1 = ((quad + 4) ^ (la & 7)) * 8;

    const f32x4 fzero = {0.f, 0.f, 0.f, 0.f};
    f32x4 acc[4][4];
    #pragma unroll
    for (int i = 0; i < 4; ++i)
        #pragma unroll
        for (int j = 0; j < 4; ++j) acc[i][j] = fzero;

    #pragma unroll
    for (int j = 0; j < 4; ++j) {
        const int fc = j * 256 + tid;
        GLOAD_LDS((const char*)abase + fc * 16, (char*)As[0] + fc * 16);
        GLOAD_LDS((const char*)bbase + fc * 16, (char*)Bs[0] + fc * 16);
    }
    __syncthreads();

    for (int kt = 0; kt < 16; ++kt) {
        if (kt < 15) {
            const char* asrc = (const char*)(abase + (kt + 1) * 8192);
            const char* bsrc = (const char*)(bbase + (kt + 1) * 8192);
            char* adst = (char*)As[(kt + 1) & 1];
            char* bdst = (char*)Bs[(kt + 1) & 1];
            #pragma unroll
            for (int j = 0; j < 4; ++j) {
                const int fc = j * 256 + tid;
                GLOAD_LDS(asrc + fc * 16, adst + fc * 16);
                GLOAD_LDS(bsrc + fc * 16, bdst + fc * 16);
            }
        }

        const unsigned short* Ab = As[kt & 1];
        const unsigned short* Bb = Bs[kt & 1];
        #pragma unroll
        for (int ks2 = 0; ks2 < 2; ++ks2) {
            const int sw = ks2 ? sw1 : sw0;
            bf16x8 af[4], bfr[4];
            #pragma unroll
            for (int mt = 0; mt < 4; ++mt) af[mt]  = *(const bf16x8*)&Ab[(wm + mt * 16 + la) * 64 + sw];
            #pragma unroll
            for (int nt = 0; nt < 4; ++nt) bfr[nt] = *(const bf16x8*)&Bb[(wn + nt * 16 + la) * 64 + sw];
            #pragma unroll
            for (int mt = 0; mt < 4; ++mt)
                #pragma unroll
                for (int nt = 0; nt < 4; ++nt)
                    acc[mt][nt] = __builtin_amdgcn_mfma_f32_16x16x32_bf16(af[mt], bfr[nt], acc[mt][nt], 0, 0, 0);
        }
        __syncthreads();
    }

    const int m0 = mtb * 128, n0 = ntb * 128;
    #pragma unroll
    for (int nt = 0; nt < 4; ++nt) {
        const int n = n0 + wn + nt * 16 + la;
        const float bv = bias[n];
        #pragma unroll
        for (int mt = 0; mt < 4; ++mt)
            #pragma unroll
            for (int r = 0; r < 4; ++r) {
                const int m = m0 + wm + mt * 16 + quad * 4 + r;
                out[(size_t)m * HDIM + n] = acc[mt][nt][r] + bv;
            }
    }
}

// ---------------------------------------------------------------------------
extern "C" void kernel_launch(void* const* d_in, const int* in_sizes, int n_in,
                              void* d_out, int out_size, void* d_ws, size_t ws_size,
                              hipStream_t stream) {
    const float* x    = (const float*)d_in[0];
    const float* W    = (const float*)d_in[1];
    const float* bias = (const float*)d_in[2];
    float* out = (float*)d_out;

    // ws layout (bytes): ctxt 8M | xb 8M | xt 8M | wbt 2M
    unsigned short* ctxt = (unsigned short*)d_ws;
    unsigned short* xbp  = (unsigned short*)((char*)d_ws + ( 8u << 20));
    unsigned short* xtp  = (unsigned short*)((char*)d_ws + (16u << 20));
    unsigned short* wbt  = (unsigned short*)((char*)d_ws + (24u << 20));

    prep_kernel<<<dim3(32, 32), 256, 0, stream>>>(x, W, xbp, xtp, wbt);
    attn_kernel<<<dim3(32, 16), 256, 0, stream>>>(xbp, xtp, ctxt);
    proj_kernel<<<dim3(8, 32), 256, 0, stream>>>(ctxt, wbt, bias, out);
}

// Round 6
// 144.304 us; speedup vs baseline: 1.0683x; 1.0040x over previous
//
#include <hip/hip_runtime.h>
#include <stdint.h>

#define NH     16
#define LSEQ   2048
#define DH     64
#define HDIM   1024
#define BATCH  2

typedef __attribute__((ext_vector_type(8))) short bf16x8;
typedef __attribute__((ext_vector_type(4))) short bf16x4;
typedef __attribute__((ext_vector_type(8))) unsigned short u16x8;
typedef __attribute__((ext_vector_type(4))) float f32x4;
typedef __attribute__((ext_vector_type(16))) float f32x16;

// fp32 -> bf16 (RNE)
static __device__ inline unsigned short f2bs(float f) {
    union { float f; uint32_t u; } v; v.f = f;
    uint32_t u = v.u;
    return (unsigned short)((u + 0x7FFFu + ((u >> 16) & 1u)) >> 16);
}

static __device__ inline unsigned int cvtpk(float lo, float hi) {
    unsigned int r;
    asm("v_cvt_pk_bf16_f32 %0, %1, %2" : "=v"(r) : "v"(lo), "v"(hi));
    return r;
}
static __device__ inline void pl32swap(unsigned int &a, unsigned int &b) {
    asm volatile("v_permlane32_swap_b32 %0, %1" : "+v"(a), "+v"(b));
}

#define GLOAD_LDS(gp, lp) \
    __builtin_amdgcn_global_load_lds((const __attribute__((address_space(1))) void*)(gp), \
                                     (__attribute__((address_space(3))) void*)(lp), 16, 0, 0)

#define MFMA32(A, B, C) __builtin_amdgcn_mfma_f32_32x32x16_bf16((A), (B), (C), 0, 0, 0)

// sqrt(0.125 * log2(e)) — folded into xb so (sQ)·(sK) carries the softmax scale
#define QK_SCALE 0.42466083f

// ---------------------------------------------------------------------------
// Kernel 1: prep. grid (32 lt, 32 bh) = 1024 blocks, 256 thr.
//  a) threads 0..127: W fp32 -> bf16 swizzled 128x64 tiles (128 chunks/block)
//  b) all threads: x -> xb (scaled, row-major [r][d], byte^((r&7)<<4) swizzle;
//     serves BOTH Q-frag loads and K staging) and xt (V^T row-major [d][kv],
//     byte^((d&7)<<4) swizzle) for the 32x32-MFMA attn kernel.
// ---------------------------------------------------------------------------
__global__ __launch_bounds__(256) void prep_kernel(const float* __restrict__ x,
                                                   const float* __restrict__ W,
                                                   unsigned short* __restrict__ xb,
                                                   unsigned short* __restrict__ xt,
                                                   unsigned short* __restrict__ wbt) {
    const int lt = blockIdx.x, bh = blockIdx.y;
    const int bid = bh * 32 + lt;
    const int t = threadIdx.x;

    if (t < 128) {
        const int gid = bid * 128 + t;
        const int n  = gid >> 7;
        const int kc = gid & 127;
        const float* src = W + (size_t)n * 1024 + kc * 8;
        float4 f0 = *(const float4*)(src);
        float4 f1 = *(const float4*)(src + 4);
        u16x8 v;
        v[0]=f2bs(f0.x); v[1]=f2bs(f0.y); v[2]=f2bs(f0.z); v[3]=f2bs(f0.w);
        v[4]=f2bs(f1.x); v[5]=f2bs(f1.y); v[6]=f2bs(f1.z); v[7]=f2bs(f1.w);
        const int nt = n >> 7, rn = n & 127;
        const int kt = kc >> 3, c = kc & 7;
        *(u16x8*)(wbt + (((size_t)nt * 16 + kt) * 128 + rn) * 64 + ((c ^ (rn & 7)) * 8)) = v;
    }

    const int b = bh >> 4, h = bh & 15;
    const int r = t >> 2, cp = t & 3;

    __shared__ __align__(16) unsigned short Sm[64][72];

    const float* src = x + ((size_t)(b * LSEQ + lt * 64 + r)) * HDIM + h * DH + cp * 16;
    float4 f0 = *(const float4*)(src);
    float4 f1 = *(const float4*)(src + 4);
    float4 f2 = *(const float4*)(src + 8);
    float4 f3 = *(const float4*)(src + 12);
    u16x8 lo, hi;
    lo[0]=f2bs(f0.x); lo[1]=f2bs(f0.y); lo[2]=f2bs(f0.z); lo[3]=f2bs(f0.w);
    lo[4]=f2bs(f1.x); lo[5]=f2bs(f1.y); lo[6]=f2bs(f1.z); lo[7]=f2bs(f1.w);
    hi[0]=f2bs(f2.x); hi[1]=f2bs(f2.y); hi[2]=f2bs(f2.z); hi[3]=f2bs(f2.w);
    hi[4]=f2bs(f3.x); hi[5]=f2bs(f3.y); hi[6]=f2bs(f3.z); hi[7]=f2bs(f3.w);
    u16x8 slo, shi;
    slo[0]=f2bs(f0.x*QK_SCALE); slo[1]=f2bs(f0.y*QK_SCALE); slo[2]=f2bs(f0.z*QK_SCALE); slo[3]=f2bs(f0.w*QK_SCALE);
    slo[4]=f2bs(f1.x*QK_SCALE); slo[5]=f2bs(f1.y*QK_SCALE); slo[6]=f2bs(f1.z*QK_SCALE); slo[7]=f2bs(f1.w*QK_SCALE);
    shi[0]=f2bs(f2.x*QK_SCALE); shi[1]=f2bs(f2.y*QK_SCALE); shi[2]=f2bs(f2.z*QK_SCALE); shi[3]=f2bs(f2.w*QK_SCALE);
    shi[4]=f2bs(f3.x*QK_SCALE); shi[5]=f2bs(f3.y*QK_SCALE); shi[6]=f2bs(f3.z*QK_SCALE); shi[7]=f2bs(f3.w*QK_SCALE);

    {   // xb: scaled [r][d] row-major, short-offset XOR (r&7)*8
        unsigned short* xrow = xb + (size_t)bid * 4096 + r * 64;
        const int xrs = (r & 7) * 8;
        *(u16x8*)(xrow + ((cp * 16 + 0) ^ xrs)) = slo;
        *(u16x8*)(xrow + ((cp * 16 + 8) ^ xrs)) = shi;
    }
    *(u16x8*)&Sm[r][cp * 16]     = lo;
    *(u16x8*)&Sm[r][cp * 16 + 8] = hi;
    __syncthreads();

    {   // xt: V^T [d][kv] row-major, short-offset XOR (d&7)*8
        const int d = t >> 2, part = (t & 3) * 16;
        unsigned short* vrow = xt + (size_t)bid * 4096 + d * 64;
        const int xrs = (d & 7) * 8;
        u16x8 g0, g1;
        #pragma unroll
        for (int i = 0; i < 8; ++i) g0[i] = Sm[part + i][d];
        #pragma unroll
        for (int i = 0; i < 8; ++i) g1[i] = Sm[part + 8 + i][d];
        *(u16x8*)(vrow + ((part + 0) ^ xrs)) = g0;
        *(u16x8*)(vrow + ((part + 8) ^ xrs)) = g1;
    }
}

// ---------------------------------------------------------------------------
// Kernel 2: flash attention, 32x32 MFMA, swapped-operand QK (q = lane&31),
// in-register softmax, cvt_pk+permlane32_swap P->PA repack (T12), PV at
// full-rate 32x32x16. r15's 4-buffer depth-2 counted-vmcnt pipeline kept.
// grid (32 bh, 16 qt) = 512 blocks, 256 thr (4 waves x 32 q-rows), LDS 64KB.
// ---------------------------------------------------------------------------
__global__ __launch_bounds__(256) void attn_kernel(const unsigned short* __restrict__ xb,
                                                   const unsigned short* __restrict__ xt,
                                                   unsigned short* __restrict__ ctxt) {
    const int bh = blockIdx.x;
    const int qt = blockIdx.y;
    const int tid = threadIdx.x;
    const int w = tid >> 6, lane = tid & 63;
    const int l31 = lane & 31, hh = lane >> 5;

    __shared__ __align__(16) unsigned short KL[4][4096];
    __shared__ __align__(16) unsigned short VL[4][4096];

    const char* xbB = (const char*)(xb + (size_t)bh * 32 * 4096);
    const char* xtB = (const char*)(xt + (size_t)bh * 32 * 4096);

    // --- Q hoist: B-frags, lane holds col q = l31, k=d slices of 16 ---
    bf16x8 qf[4];
    {
        const int qtile = qt * 2 + (w >> 1);
        const int rq = (w & 1) * 32 + l31;
        const char* qbase = xbB + (size_t)qtile * 8192 + rq * 128;
        const int qxr = (rq & 7) << 4;
        #pragma unroll
        for (int ds = 0; ds < 4; ++ds)
            qf[ds] = *(const bf16x8*)(qbase + ((ds * 32 + hh * 16) ^ qxr));
    }

    f32x16 accA, accB;
    #pragma unroll
    for (int r = 0; r < 16; ++r) { accA[r] = 0.f; accB[r] = 0.f; }
    float lp = 0.f;

    const int soff = tid * 16;
    // prologue: stage tiles 0 and 1
    #pragma unroll
    for (int j = 0; j < 2; ++j) {
        const char* kps = xbB + j * 8192;
        const char* vps = xtB + j * 8192;
        GLOAD_LDS(kps + soff,        (char*)KL[j] + soff);
        GLOAD_LDS(kps + 4096 + soff, (char*)KL[j] + 4096 + soff);
        GLOAD_LDS(vps + soff,        (char*)VL[j] + soff);
        GLOAD_LDS(vps + 4096 + soff, (char*)VL[j] + 4096 + soff);
    }
    asm volatile("s_waitcnt vmcnt(4)" ::: "memory");
    __builtin_amdgcn_s_barrier();

    const int kxr = (l31 & 7) << 4;   // row-XOR for K and V frag reads

    for (int tt = 0; tt < 32; ++tt) {
        if (tt < 30) {
            const char* kps = xbB + (tt + 2) * 8192;
            const char* vps = xtB + (tt + 2) * 8192;
            char* kdst = (char*)KL[(tt + 2) & 3];
            char* vdst = (char*)VL[(tt + 2) & 3];
            GLOAD_LDS(kps + soff,        kdst + soff);
            GLOAD_LDS(kps + 4096 + soff, kdst + 4096 + soff);
            GLOAD_LDS(vps + soff,        vdst + soff);
            GLOAD_LDS(vps + 4096 + soff, vdst + 4096 + soff);
        }

        // --- QK: D[kv][q] = K . Q, two 32-kv tiles ---
        const char* kb0 = (const char*)KL[tt & 3] + l31 * 128;
        const char* kb1 = kb0 + 4096;
        f32x16 s0, s1;
        #pragma unroll
        for (int r = 0; r < 16; ++r) { s0[r] = 0.f; s1[r] = 0.f; }
        __builtin_amdgcn_s_setprio(1);
        #pragma unroll
        for (int ds = 0; ds < 4; ++ds) {
            const int off = (ds * 32 + hh * 16) ^ kxr;
            bf16x8 kfa = *(const bf16x8*)(kb0 + off);
            bf16x8 kfb = *(const bf16x8*)(kb1 + off);
            s0 = MFMA32(kfa, qf[ds], s0);
            s1 = MFMA32(kfb, qf[ds], s1);
        }
        __builtin_amdgcn_s_setprio(0);

        // --- exp2 (lane-local row) + sum + pack to PA frags ---
        f32x16 e0, e1;
        {
            float ls = 0.f;
            #pragma unroll
            for (int r = 0; r < 16; ++r) {
                e0[r] = __builtin_amdgcn_exp2f(s0[r]);
                e1[r] = __builtin_amdgcn_exp2f(s1[r]);
                ls += e0[r] + e1[r];
            }
            lp += ls;
        }
        bf16x8 pa[4];
        #pragma unroll
        for (int ks = 0; ks < 4; ++ks) {
            const int r0 = (ks & 1) * 8;
            unsigned int x0, y0, x1, y1;
            if (ks < 2) {
                x0 = cvtpk(e0[r0 + 0], e0[r0 + 1]);
                y0 = cvtpk(e0[r0 + 4], e0[r0 + 5]);
                x1 = cvtpk(e0[r0 + 2], e0[r0 + 3]);
                y1 = cvtpk(e0[r0 + 6], e0[r0 + 7]);
            } else {
                x0 = cvtpk(e1[r0 + 0], e1[r0 + 1]);
                y0 = cvtpk(e1[r0 + 4], e1[r0 + 5]);
                x1 = cvtpk(e1[r0 + 2], e1[r0 + 3]);
                y1 = cvtpk(e1[r0 + 6], e1[r0 + 7]);
            }
            pl32swap(x0, y0);
            pl32swap(x1, y1);
            union { unsigned int u[4]; bf16x8 v; } pu;
            pu.u[0] = x0; pu.u[1] = x1; pu.u[2] = y0; pu.u[3] = y1;
            pa[ks] = pu.v;
        }

        if (tt < 30) {
            asm volatile("s_waitcnt vmcnt(4)" ::: "memory");
        } else {
            asm volatile("s_waitcnt vmcnt(0)" ::: "memory");
        }
        __builtin_amdgcn_s_barrier();

        // --- PV: O[q][d] += PA . V, two 32-d tiles ---
        const char* vb0 = (const char*)VL[tt & 3] + l31 * 128;
        const char* vb1 = vb0 + 4096;
        __builtin_amdgcn_s_setprio(1);
        #pragma unroll
        for (int ks = 0; ks < 4; ++ks) {
            const int off = (ks * 32 + hh * 16) ^ kxr;
            bf16x8 vfa = *(const bf16x8*)(vb0 + off);
            bf16x8 vfb = *(const bf16x8*)(vb1 + off);
            accA = MFMA32(pa[ks], vfa, accA);
            accB = MFMA32(pa[ks], vfb, accB);
        }
        __builtin_amdgcn_s_setprio(0);
    }

    // --- epilogue ---
    lp += __shfl_xor(lp, 32);          // partner half holds the other 32 kv's
    const float inv = 1.0f / lp;
    __syncthreads();
    float* invL = (float*)KL;          // reuse LDS
    invL[w * 32 + l31] = inv;
    __syncthreads();

    const int b = bh >> 4, hd = bh & 15;
    const int mt = b * 16 + qt;
    unsigned short* tbase = ctxt + ((size_t)mt * 16 + hd) * 128 * 64;
    const int col0 = l31, col1 = 32 + l31;
    const int c80 = col0 >> 3, c81 = col1 >> 3, ce = col0 & 7;
    #pragma unroll
    for (int r = 0; r < 16; ++r) {
        const int crow = (r & 3) + 8 * (r >> 2) + 4 * hh;
        const float iv = invL[w * 32 + crow];
        const int rr = w * 32 + crow;
        unsigned short* rowp = tbase + rr * 64;
        const int sw = rr & 7;
        rowp[((c80 ^ sw) * 8) + ce] = f2bs(accA[r] * iv);
        rowp[((c81 ^ sw) * 8) + ce] = f2bs(accB[r] * iv);
    }
}

// ---------------------------------------------------------------------------
// Kernel 3: out = ctx @ W^T + b. 128x128 tile, BK=64, double-buffered LDS,
// one barrier/iter, flat global_load_lds of pre-swizzled tiles.
// grid (8 n, 32 m), block 256 = 4 waves (2x2 64x64 quadrants).
// ---------------------------------------------------------------------------
__global__ __launch_bounds__(256) void proj_kernel(const unsigned short* __restrict__ ctxt,
                                                   const unsigned short* __restrict__ wbt,
                                                   const float* __restrict__ bias,
                                                   float* __restrict__ out) {
    const int ntb = blockIdx.x;
    const int mtb = blockIdx.y;
    const int tid = threadIdx.x;
    const int w = tid >> 6, lane = tid & 63;
    const int la = lane & 15, quad = lane >> 4;
    const int wm = (w >> 1) * 64, wn = (w & 1) * 64;

    __shared__ __align__(16) unsigned short As[2][8192];
    __shared__ __align__(16) unsigned short Bs[2][8192];

    const unsigned short* abase = ctxt + (size_t)mtb * 16 * 8192;
    const unsigned short* bbase = wbt  + (size_t)ntb * 16 * 8192;

    const int sw0 = ((quad)     ^ (la & 7)) * 8;
    const int sw1 = ((quad + 4) ^ (la & 7)) * 8;

    const f32x4 fzero = {0.f, 0.f, 0.f, 0.f};
    f32x4 acc[4][4];
    #pragma unroll
    for (int i = 0; i < 4; ++i)
        #pragma unroll
        for (int j = 0; j < 4; ++j) acc[i][j] = fzero;

    #pragma unroll
    for (int j = 0; j < 4; ++j) {
        const int fc = j * 256 + tid;
        GLOAD_LDS((const char*)abase + fc * 16, (char*)As[0] + fc * 16);
        GLOAD_LDS((const char*)bbase + fc * 16, (char*)Bs[0] + fc * 16);
    }
    __syncthreads();

    for (int kt = 0; kt < 16; ++kt) {
        if (kt < 15) {
            const char* asrc = (const char*)(abase + (kt + 1) * 8192);
            const char* bsrc = (const char*)(bbase + (kt + 1) * 8192);
            char* adst = (char*)As[(kt + 1) & 1];
            char* bdst = (char*)Bs[(kt + 1) & 1];
            #pragma unroll
            for (int j = 0; j < 4; ++j) {
                const int fc = j * 256 + tid;
                GLOAD_LDS(asrc + fc * 16, adst + fc * 16);
                GLOAD_LDS(bsrc + fc * 16, bdst + fc * 16);
            }
        }

        const unsigned short* Ab = As[kt & 1];
        const unsigned short* Bb = Bs[kt & 1];
        #pragma unroll
        for (int ks2 = 0; ks2 < 2; ++ks2) {
            const int sw = ks2 ? sw1 : sw0;
            bf16x8 af[4], bfr[4];
            #pragma unroll
            for (int mt = 0; mt < 4; ++mt) af[mt]  = *(const bf16x8*)&Ab[(wm + mt * 16 + la) * 64 + sw];
            #pragma unroll
            for (int nt = 0; nt < 4; ++nt) bfr[nt] = *(const bf16x8*)&Bb[(wn + nt * 16 + la) * 64 + sw];
            #pragma unroll
            for (int mt = 0; mt < 4; ++mt)
                #pragma unroll
                for (int nt = 0; nt < 4; ++nt)
                    acc[mt][nt] = __builtin_amdgcn_mfma_f32_16x16x32_bf16(af[mt], bfr[nt], acc[mt][nt], 0, 0, 0);
        }
        __syncthreads();
    }

    const int m0 = mtb * 128, n0 = ntb * 128;
    #pragma unroll
    for (int nt = 0; nt < 4; ++nt) {
        const int n = n0 + wn + nt * 16 + la;
        const float bv = bias[n];
        #pragma unroll
        for (int mt = 0; mt < 4; ++mt)
            #pragma unroll
            for (int r = 0; r < 4; ++r) {
                const int m = m0 + wm + mt * 16 + quad * 4 + r;
                out[(size_t)m * HDIM + n] = acc[mt][nt][r] + bv;
            }
    }
}

// ---------------------------------------------------------------------------
extern "C" void kernel_launch(void* const* d_in, const int* in_sizes, int n_in,
                              void* d_out, int out_size, void* d_ws, size_t ws_size,
                              hipStream_t stream) {
    const float* x    = (const float*)d_in[0];
    const float* W    = (const float*)d_in[1];
    const float* bias = (const float*)d_in[2];
    float* out = (float*)d_out;

    // ws layout (bytes): ctxt 8M | xb 8M | xt 8M | wbt 2M
    unsigned short* ctxt = (unsigned short*)d_ws;
    unsigned short* xbp  = (unsigned short*)((char*)d_ws + ( 8u << 20));
    unsigned short* xtp  = (unsigned short*)((char*)d_ws + (16u << 20));
    unsigned short* wbt  = (unsigned short*)((char*)d_ws + (24u << 20));

    prep_kernel<<<dim3(32, 32), 256, 0, stream>>>(x, W, xbp, xtp, wbt);
    attn_kernel<<<dim3(32, 16), 256, 0, stream>>>(xbp, xtp, ctxt);
    proj_kernel<<<dim3(8, 32), 256, 0, stream>>>(ctxt, wbt, bias, out);
}

// Round 8
// 142.796 us; speedup vs baseline: 1.0796x; 1.0106x over previous
//
#include <hip/hip_runtime.h>
#include <stdint.h>

#define NH     16
#define LSEQ   2048
#define DH     64
#define HDIM   1024
#define BATCH  2

typedef __attribute__((ext_vector_type(8))) short bf16x8;
typedef __attribute__((ext_vector_type(8))) unsigned short u16x8;
typedef __attribute__((ext_vector_type(4))) float f32x4;
typedef __attribute__((ext_vector_type(16))) float f32x16;

// fp32 -> bf16 (RNE)
static __device__ inline unsigned short f2bs(float f) {
    union { float f; uint32_t u; } v; v.f = f;
    uint32_t u = v.u;
    return (unsigned short)((u + 0x7FFFu + ((u >> 16) & 1u)) >> 16);
}

static __device__ inline unsigned int cvtpk(float lo, float hi) {
    unsigned int r;
    asm("v_cvt_pk_bf16_f32 %0, %1, %2" : "=v"(r) : "v"(lo), "v"(hi));
    return r;
}
static __device__ inline void pl32swap(unsigned int &a, unsigned int &b) {
    asm volatile("v_permlane32_swap_b32 %0, %1" : "+v"(a), "+v"(b));
}

#define GLOAD_LDS(gp, lp) \
    __builtin_amdgcn_global_load_lds((const __attribute__((address_space(1))) void*)(gp), \
                                     (__attribute__((address_space(3))) void*)(lp), 16, 0, 0)

#define MFMA32(A, B, C) __builtin_amdgcn_mfma_f32_32x32x16_bf16((A), (B), (C), 0, 0, 0)

// sqrt(0.125 * log2(e)) — folded into xb so (sQ)·(sK) carries the softmax scale
#define QK_SCALE 0.42466083f

// ---------------------------------------------------------------------------
// Kernel 1: prep. grid (32 lt, 32 bh) = 1024 blocks, 256 thr.
//  a) threads 0..127: W fp32 -> bf16 swizzled 128x64 tiles (128 chunks/block)
//  b) all threads: x -> xb (scaled, FRAG-MAJOR: addr16 = st*2048 + ds*512 +
//     lane*8, data = X[st*32+(lane&31)][ds*16+(lane>>5)*8..+8]) serving both
//     Q and K register-direct loads, and xt (V^T frag-major: tile*4096 +
//     side*2048 + ks*512 + lane*8, data = V^T[side*32+(lane&31)]
//     [tile*64+ks*16+(lane>>5)*8..+8]) for register-direct V loads.
// ---------------------------------------------------------------------------
__global__ __launch_bounds__(256) void prep_kernel(const float* __restrict__ x,
                                                   const float* __restrict__ W,
                                                   unsigned short* __restrict__ xb,
                                                   unsigned short* __restrict__ xt,
                                                   unsigned short* __restrict__ wbt) {
    const int lt = blockIdx.x, bh = blockIdx.y;
    const int bid = bh * 32 + lt;
    const int t = threadIdx.x;

    if (t < 128) {
        const int gid = bid * 128 + t;
        const int n  = gid >> 7;
        const int kc = gid & 127;
        const float* src = W + (size_t)n * 1024 + kc * 8;
        float4 f0 = *(const float4*)(src);
        float4 f1 = *(const float4*)(src + 4);
        u16x8 v;
        v[0]=f2bs(f0.x); v[1]=f2bs(f0.y); v[2]=f2bs(f0.z); v[3]=f2bs(f0.w);
        v[4]=f2bs(f1.x); v[5]=f2bs(f1.y); v[6]=f2bs(f1.z); v[7]=f2bs(f1.w);
        const int nt = n >> 7, rn = n & 127;
        const int kt = kc >> 3, c = kc & 7;
        *(u16x8*)(wbt + (((size_t)nt * 16 + kt) * 128 + rn) * 64 + ((c ^ (rn & 7)) * 8)) = v;
    }

    const int b = bh >> 4, h = bh & 15;
    const int r = t >> 2, cp = t & 3;

    __shared__ __align__(16) unsigned short Sm[64][72];

    const float* src = x + ((size_t)(b * LSEQ + lt * 64 + r)) * HDIM + h * DH + cp * 16;
    float4 f0 = *(const float4*)(src);
    float4 f1 = *(const float4*)(src + 4);
    float4 f2 = *(const float4*)(src + 8);
    float4 f3 = *(const float4*)(src + 12);
    u16x8 lo, hi;
    lo[0]=f2bs(f0.x); lo[1]=f2bs(f0.y); lo[2]=f2bs(f0.z); lo[3]=f2bs(f0.w);
    lo[4]=f2bs(f1.x); lo[5]=f2bs(f1.y); lo[6]=f2bs(f1.z); lo[7]=f2bs(f1.w);
    hi[0]=f2bs(f2.x); hi[1]=f2bs(f2.y); hi[2]=f2bs(f2.z); hi[3]=f2bs(f2.w);
    hi[4]=f2bs(f3.x); hi[5]=f2bs(f3.y); hi[6]=f2bs(f3.z); hi[7]=f2bs(f3.w);
    u16x8 slo, shi;
    slo[0]=f2bs(f0.x*QK_SCALE); slo[1]=f2bs(f0.y*QK_SCALE); slo[2]=f2bs(f0.z*QK_SCALE); slo[3]=f2bs(f0.w*QK_SCALE);
    slo[4]=f2bs(f1.x*QK_SCALE); slo[5]=f2bs(f1.y*QK_SCALE); slo[6]=f2bs(f1.z*QK_SCALE); slo[7]=f2bs(f1.w*QK_SCALE);
    shi[0]=f2bs(f2.x*QK_SCALE); shi[1]=f2bs(f2.y*QK_SCALE); shi[2]=f2bs(f2.z*QK_SCALE); shi[3]=f2bs(f2.w*QK_SCALE);
    shi[4]=f2bs(f3.x*QK_SCALE); shi[5]=f2bs(f3.y*QK_SCALE); shi[6]=f2bs(f3.z*QK_SCALE); shi[7]=f2bs(f3.w*QK_SCALE);

    {   // xb frag-major: st = lt*2 + (r>>5); ds = cp; lane = hh*32 + (r&31)
        unsigned short* xbase = xb + (size_t)bh * 131072
                              + ((size_t)lt * 2 + (r >> 5)) * 2048 + cp * 512 + (r & 31) * 8;
        *(u16x8*)(xbase)       = slo;   // hh=0 (d = cp*16 + 0..7)
        *(u16x8*)(xbase + 256) = shi;   // hh=1 (d = cp*16 + 8..15)
    }
    *(u16x8*)&Sm[r][cp * 16]     = lo;
    *(u16x8*)&Sm[r][cp * 16 + 8] = hi;
    __syncthreads();

    {   // xt frag-major: tile = lt; side = d>>5; ks = part>>4; lane = hh*32 + (d&31)
        const int d = t >> 2, part = (t & 3) * 16;
        unsigned short* vbase = xt + (size_t)bh * 131072 + (size_t)lt * 4096
                              + (d >> 5) * 2048 + (part >> 4) * 512 + (d & 31) * 8;
        u16x8 g0, g1;
        #pragma unroll
        for (int i = 0; i < 8; ++i) g0[i] = Sm[part + i][d];
        #pragma unroll
        for (int i = 0; i < 8; ++i) g1[i] = Sm[part + 8 + i][d];
        *(u16x8*)(vbase)       = g0;   // kv part..part+7   (hh=0)
        *(u16x8*)(vbase + 256) = g1;   // kv part+8..part+15 (hh=1)
    }
}

// ---------------------------------------------------------------------------
// Kernel 2: flash attention, 32x32 MFMA, ZERO LDS / ZERO barriers.
// r17: all fragments (Q/K/V) loaded register-direct from frag-major global
// layouts (L1/L2-resident; per-XCD working set ~2MB). Row-sum via MFMA
// ones-trick into accS (row-aligned with accA/accB -> barrier-free epilogue).
// grid (32 bh, 16 qt) = 512 blocks, 256 thr (4 waves x 32 q-rows).
// ---------------------------------------------------------------------------
__global__ __launch_bounds__(256, 3) void attn_kernel(const unsigned short* __restrict__ xb,
                                                      const unsigned short* __restrict__ xt,
                                                      unsigned short* __restrict__ ctxt) {
    const int bh = blockIdx.x;
    const int qt = blockIdx.y;
    const int tid = threadIdx.x;
    const int w = tid >> 6, lane = tid & 63;
    const int l31 = lane & 31, hh = lane >> 5;

    const char* xbB = (const char*)(xb + (size_t)bh * 131072);
    const char* xtB = (const char*)(xt + (size_t)bh * 131072);

    // --- Q hoist: B-frags for q-subtile st_q = qt*4 + w ---
    bf16x8 qf[4];
    {
        const char* qbase = xbB + (size_t)(qt * 4 + w) * 4096 + lane * 16;
        #pragma unroll
        for (int ds = 0; ds < 4; ++ds)
            qf[ds] = *(const bf16x8*)(qbase + ds * 1024);
    }

    // ones B-frag for the row-sum MFMA
    bf16x8 ones;
    #pragma unroll
    for (int i = 0; i < 8; ++i) ones[i] = (short)0x3F80;

    f32x16 accA, accB, accS;
    #pragma unroll
    for (int r = 0; r < 16; ++r) { accA[r] = 0.f; accB[r] = 0.f; accS[r] = 0.f; }

    const char* ka = xbB + lane * 16;   // K tile tt: + tt*8192 (+4096 for 2nd subtile)
    const char* va = xtB + lane * 16;   // V tile tt: + tt*8192 (+4096 for side 1)

    for (int tt = 0; tt < 32; ++tt) {
        // --- K frags direct to registers ---
        bf16x8 kfa[4], kfb[4];
        #pragma unroll
        for (int ds = 0; ds < 4; ++ds) {
            kfa[ds] = *(const bf16x8*)(ka + ds * 1024);
            kfb[ds] = *(const bf16x8*)(ka + 4096 + ds * 1024);
        }

        // --- QK: S^T[kv][q], two 32-kv subtiles ---
        f32x16 s0, s1;
        #pragma unroll
        for (int r = 0; r < 16; ++r) { s0[r] = 0.f; s1[r] = 0.f; }
        __builtin_amdgcn_s_setprio(1);
        #pragma unroll
        for (int ds = 0; ds < 4; ++ds) {
            s0 = MFMA32(kfa[ds], qf[ds], s0);
            s1 = MFMA32(kfb[ds], qf[ds], s1);
        }
        __builtin_amdgcn_s_setprio(0);

        // --- V frags direct to registers (latency hidden under softmax) ---
        bf16x8 vfa[4], vfb[4];
        #pragma unroll
        for (int ks = 0; ks < 4; ++ks) {
            vfa[ks] = *(const bf16x8*)(va + ks * 1024);
            vfb[ks] = *(const bf16x8*)(va + 4096 + ks * 1024);
        }
        ka += 8192;
        va += 8192;

        // --- exp2 in place (lane-local softmax rows, scale pre-folded) ---
        #pragma unroll
        for (int r = 0; r < 16; ++r) {
            s0[r] = __builtin_amdgcn_exp2f(s0[r]);
            s1[r] = __builtin_amdgcn_exp2f(s1[r]);
        }

        // --- pack P -> A-frags via cvt_pk + permlane32_swap (r16-verified) ---
        bf16x8 pa[4];
        #pragma unroll
        for (int ks = 0; ks < 4; ++ks) {
            const int r0 = (ks & 1) * 8;
            unsigned int x0, y0, x1, y1;
            if (ks < 2) {
                x0 = cvtpk(s0[r0 + 0], s0[r0 + 1]);
                y0 = cvtpk(s0[r0 + 4], s0[r0 + 5]);
                x1 = cvtpk(s0[r0 + 2], s0[r0 + 3]);
                y1 = cvtpk(s0[r0 + 6], s0[r0 + 7]);
            } else {
                x0 = cvtpk(s1[r0 + 0], s1[r0 + 1]);
                y0 = cvtpk(s1[r0 + 4], s1[r0 + 5]);
                x1 = cvtpk(s1[r0 + 2], s1[r0 + 3]);
                y1 = cvtpk(s1[r0 + 6], s1[r0 + 7]);
            }
            pl32swap(x0, y0);
            pl32swap(x1, y1);
            union { unsigned int u[4]; bf16x8 v; } pu;
            pu.u[0] = x0; pu.u[1] = x1; pu.u[2] = y0; pu.u[3] = y1;
            pa[ks] = pu.v;
        }

        // --- PV + row-sum: O += P.V ; accS += P.1 (matrix pipe, not VALU) ---
        __builtin_amdgcn_s_setprio(1);
        #pragma unroll
        for (int ks = 0; ks < 4; ++ks) {
            accA = MFMA32(pa[ks], vfa[ks], accA);
            accB = MFMA32(pa[ks], vfb[ks], accB);
            accS = MFMA32(pa[ks], ones, accS);
        }
        __builtin_amdgcn_s_setprio(0);
    }

    // --- epilogue: accS[r] is the rowsum for exactly accA[r]/accB[r]'s row ---
    const int b = bh >> 4, hd = bh & 15;
    const int mt = b * 16 + qt;
    unsigned short* tbase = ctxt + ((size_t)mt * 16 + hd) * 128 * 64;
    const int c80 = l31 >> 3, c81 = 4 + (l31 >> 3), ce = l31 & 7;
    #pragma unroll
    for (int r = 0; r < 16; ++r) {
        const float iv = 1.0f / accS[r];
        const int crow = (r & 3) + 8 * (r >> 2) + 4 * hh;
        const int rr = w * 32 + crow;
        unsigned short* rowp = tbase + rr * 64;
        const int sw = rr & 7;
        rowp[((c80 ^ sw) * 8) + ce] = f2bs(accA[r] * iv);
        rowp[((c81 ^ sw) * 8) + ce] = f2bs(accB[r] * iv);
    }
}

// ---------------------------------------------------------------------------
// Kernel 3: out = ctx @ W^T + b. 128x128 tile, BK=64, double-buffered LDS,
// one barrier/iter, flat global_load_lds of pre-swizzled tiles.
// grid (8 n, 32 m), block 256 = 4 waves (2x2 64x64 quadrants).
// ---------------------------------------------------------------------------
__global__ __launch_bounds__(256) void proj_kernel(const unsigned short* __restrict__ ctxt,
                                                   const unsigned short* __restrict__ wbt,
                                                   const float* __restrict__ bias,
                                                   float* __restrict__ out) {
    const int ntb = blockIdx.x;
    const int mtb = blockIdx.y;
    const int tid = threadIdx.x;
    const int w = tid >> 6, lane = tid & 63;
    const int la = lane & 15, quad = lane >> 4;
    const int wm = (w >> 1) * 64, wn = (w & 1) * 64;

    __shared__ __align__(16) unsigned short As[2][8192];
    __shared__ __align__(16) unsigned short Bs[2][8192];

    const unsigned short* abase = ctxt + (size_t)mtb * 16 * 8192;
    const unsigned short* bbase = wbt  + (size_t)ntb * 16 * 8192;

    const int sw0 = ((quad)     ^ (la & 7)) * 8;
    const int sw1 = ((quad + 4) ^ (la & 7)) * 8;

    const f32x4 fzero = {0.f, 0.f, 0.f, 0.f};
    f32x4 acc[4][4];
    #pragma unroll
    for (int i = 0; i < 4; ++i)
        #pragma unroll
        for (int j = 0; j < 4; ++j) acc[i][j] = fzero;

    #pragma unroll
    for (int j = 0; j < 4; ++j) {
        const int fc = j * 256 + tid;
        GLOAD_LDS((const char*)abase + fc * 16, (char*)As[0] + fc * 16);
        GLOAD_LDS((const char*)bbase + fc * 16, (char*)Bs[0] + fc * 16);
    }
    __syncthreads();

    for (int kt = 0; kt < 16; ++kt) {
        if (kt < 15) {
            const char* asrc = (const char*)(abase + (kt + 1) * 8192);
            const char* bsrc = (const char*)(bbase + (kt + 1) * 8192);
            char* adst = (char*)As[(kt + 1) & 1];
            char* bdst = (char*)Bs[(kt + 1) & 1];
            #pragma unroll
            for (int j = 0; j < 4; ++j) {
                const int fc = j * 256 + tid;
                GLOAD_LDS(asrc + fc * 16, adst + fc * 16);
                GLOAD_LDS(bsrc + fc * 16, bdst + fc * 16);
            }
        }

        const unsigned short* Ab = As[kt & 1];
        const unsigned short* Bb = Bs[kt & 1];
        #pragma unroll
        for (int ks2 = 0; ks2 < 2; ++ks2) {
            const int sw = ks2 ? sw1 : sw0;
            bf16x8 af[4], bfr[4];
            #pragma unroll
            for (int mt = 0; mt < 4; ++mt) af[mt]  = *(const bf16x8*)&Ab[(wm + mt * 16 + la) * 64 + sw];
            #pragma unroll
            for (int nt = 0; nt < 4; ++nt) bfr[nt] = *(const bf16x8*)&Bb[(wn + nt * 16 + la) * 64 + sw];
            #pragma unroll
            for (int mt = 0; mt < 4; ++mt)
                #pragma unroll
                for (int nt = 0; nt < 4; ++nt)
                    acc[mt][nt] = __builtin_amdgcn_mfma_f32_16x16x32_bf16(af[mt], bfr[nt], acc[mt][nt], 0, 0, 0);
        }
        __syncthreads();
    }

    const int m0 = mtb * 128, n0 = ntb * 128;
    #pragma unroll
    for (int nt = 0; nt < 4; ++nt) {
        const int n = n0 + wn + nt * 16 + la;
        const float bv = bias[n];
        #pragma unroll
        for (int mt = 0; mt < 4; ++mt)
            #pragma unroll
            for (int r = 0; r < 4; ++r) {
                const int m = m0 + wm + mt * 16 + quad * 4 + r;
                out[(size_t)m * HDIM + n] = acc[mt][nt][r] + bv;
            }
    }
}

// ---------------------------------------------------------------------------
extern "C" void kernel_launch(void* const* d_in, const int* in_sizes, int n_in,
                              void* d_out, int out_size, void* d_ws, size_t ws_size,
                              hipStream_t stream) {
    const float* x    = (const float*)d_in[0];
    const float* W    = (const float*)d_in[1];
    const float* bias = (const float*)d_in[2];
    float* out = (float*)d_out;

    // ws layout (bytes): ctxt 8M | xb 8M | xt 8M | wbt 2M
    unsigned short* ctxt = (unsigned short*)d_ws;
    unsigned short* xbp  = (unsigned short*)((char*)d_ws + ( 8u << 20));
    unsigned short* xtp  = (unsigned short*)((char*)d_ws + (16u << 20));
    unsigned short* wbt  = (unsigned short*)((char*)d_ws + (24u << 20));

    prep_kernel<<<dim3(32, 32), 256, 0, stream>>>(x, W, xbp, xtp, wbt);
    attn_kernel<<<dim3(32, 16), 256, 0, stream>>>(xbp, xtp, ctxt);
    proj_kernel<<<dim3(8, 32), 256, 0, stream>>>(ctxt, wbt, bias, out);
}